// Round 1
// baseline (2114.364 us; speedup 1.0000x reference)
//
#include <hip/hip_runtime.h>
#include <math.h>

#define PI_D 3.14159265358979323846

// N=10 images, E=64 ch, H=128, W=256, M=16 modes, L=4 layers
// HW = 32768

__device__ __forceinline__ float gelu_f(float v){
  return 0.5f*v*(1.0f + erff(v*0.70710678118654752440f));
}

// ---------------- twiddle tables ----------------
// twFwW: [w 256][y 16][2]  e^{-2pi i y w /256}
// twFwH: [h 128][m 32][2]  e^{-2pi i x_m h /128}, x_m = m<16 ? m : 96+m
// twBwH: [m 32][h 128][2]  e^{+2pi i x_m h /128}
// twBwW: [w 256][y 16][2]  e^{+2pi i y w /256}
__global__ __launch_bounds__(256) void k_tables(float* __restrict__ twFwW, float* __restrict__ twFwH,
                                                float* __restrict__ twBwH, float* __restrict__ twBwW){
  int id = blockIdx.x*256 + threadIdx.x;
  int tab = id >> 12, j = id & 4095;
  if (tab == 0){
    int w = j >> 4, y = j & 15;
    double ang = -2.0*PI_D*(double)((y*w) & 255)/256.0;
    twFwW[j*2]   = (float)cos(ang);
    twFwW[j*2+1] = (float)sin(ang);
  } else if (tab == 1){
    int m = j & 31;                     // j = h*32 + m
    int h = j >> 5;
    int xm = (m < 16) ? m : (96 + m);
    double ang = -2.0*PI_D*(double)((xm*h) & 127)/128.0;
    twFwH[j*2]   = (float)cos(ang);
    twFwH[j*2+1] = (float)sin(ang);
  } else if (tab == 2){
    int m = j >> 7, h = j & 127;        // j = m*128 + h
    int xm = (m < 16) ? m : (96 + m);
    double ang = 2.0*PI_D*(double)((xm*h) & 127)/128.0;
    twBwH[j*2]   = (float)cos(ang);
    twBwH[j*2+1] = (float)sin(ang);
  } else {
    int w = j >> 4, y = j & 15;
    double ang = 2.0*PI_D*(double)((y*w) & 255)/256.0;
    twBwW[j*2]   = (float)cos(ang);
    twBwW[j*2+1] = (float)sin(ang);
  }
}

// ---------------- collapsed 2x2 conv kernels (per upsample parity) ----------------
// K[rs][o][i][a*2+b];  rowsets: r=0: a0={kh0}, a1={kh1,kh2}; r=1: a0={kh0,kh1}, a1={kh2}
__global__ __launch_bounds__(256) void k_buildK(const float* __restrict__ w, float* __restrict__ K){
  int id = blockIdx.x*256 + threadIdx.x; // 0..4095 = o*64+i
  float w9[9];
  #pragma unroll
  for (int k=0;k<9;++k) w9[k] = w[id*9 + k];
  #pragma unroll
  for (int r=0;r<2;++r){
    #pragma unroll
    for (int s=0;s<2;++s){
      int rs = r*2+s;
      #pragma unroll
      for (int a=0;a<2;++a){
        int klo = (r==0) ? (a==0?0:1) : (a==0?0:2);
        int khi = (r==0) ? (a==0?0:2) : (a==0?1:2);
        #pragma unroll
        for (int b=0;b<2;++b){
          int llo = (s==0) ? (b==0?0:1) : (b==0?0:2);
          int lhi = (s==0) ? (b==0?0:2) : (b==0?1:2);
          float sum = 0.f;
          for (int kh=klo; kh<=khi; ++kh)
            for (int kw=llo; kw<=lhi; ++kw)
              sum += w9[kh*3+kw];
          K[(rs*4096 + id)*4 + a*2 + b] = sum;
        }
      }
    }
  }
}

// ---------------- updim 1x1 conv (C=2 -> E=64) ----------------
__global__ __launch_bounds__(256) void k_updim(const float* __restrict__ sv, const float* __restrict__ w,
                                               const float* __restrict__ b, float* __restrict__ u){
  size_t idx = (size_t)blockIdx.x*256 + threadIdx.x;   // over 10*64*32768
  int pos = (int)(idx & 32767);
  int e   = (int)((idx >> 15) & 63);
  int n   = (int)(idx >> 21);
  float v0 = sv[(size_t)n*65536 + pos];
  float v1 = sv[(size_t)n*65536 + 32768 + pos];
  u[idx] = w[e*2+0]*v0 + w[e*2+1]*v1 + b[e];
}

// ---------------- collapsed conv: one parity per block-group ----------------
// blockIdx.x = ((rs*10 + n)*128 + p)*4 + qt    (20480 blocks)
__global__ __launch_bounds__(256) void k_conv(const float* __restrict__ u, const float* __restrict__ K,
                                              const float* __restrict__ sb, float* __restrict__ y00,
                                              float* __restrict__ part){
  __shared__ float XS[64*2*66]; // [i][a][c]; c=0..65 -> col q0-1+c
  int bid = blockIdx.x;
  int qt4 = bid & 3;
  int p   = (bid >> 2) & 127;
  int t9  = bid >> 9;          // rs*10 + n
  int n   = t9 % 10;
  int rs  = t9 / 10;
  int r = rs >> 1, s = rs & 1;
  int q0 = qt4 * 64;
  int row0 = (r == 0) ? (p - 1) : p;
  int row1 = row0 + 1;
  int tid = threadIdx.x;

  for (int t = tid; t < 64*2*66; t += 256){
    int c  = t % 66;
    int ia = t / 66;       // i*2 + a
    int a  = ia & 1;
    int i  = ia >> 1;
    int row = a ? row1 : row0;
    int col = q0 - 1 + c;
    float v = 0.f;
    if (row >= 0 && row < 128 && col >= 0 && col < 256)
      v = u[((size_t)(n*64 + i)*128 + row)*256 + col];
    XS[t] = v;
  }
  __syncthreads();

  int qt = tid & 15, ot = tid >> 4;
  int ob = ot * 4;
  float acc[4][4];
  #pragma unroll
  for (int oo=0;oo<4;++oo){
    float b = sb[ob+oo];
    #pragma unroll
    for (int j=0;j<4;++j) acc[oo][j] = b;
  }
  int cb0 = qt*4 + s;   // x[j] pairs with tap b=0; x[j+1] with b=1
  for (int i = 0; i < 64; ++i){
    const float* xr0 = XS + (i*2 + 0)*66 + cb0;
    const float* xr1 = xr0 + 66;
    float x0[5], x1[5];
    #pragma unroll
    for (int j=0;j<5;++j){ x0[j]=xr0[j]; x1[j]=xr1[j]; }
    #pragma unroll
    for (int oo = 0; oo < 4; ++oo){
      const float4 kv = *(const float4*)(K + (size_t)(rs*4096 + (ob+oo)*64 + i)*4);
      #pragma unroll
      for (int j = 0; j < 4; ++j)
        acc[oo][j] += kv.x*x0[j] + kv.y*x0[j+1] + kv.z*x1[j] + kv.w*x1[j+1];
    }
  }

  __syncthreads();
  float* red = XS; // reuse: [64 o][16 qt][2]
  #pragma unroll
  for (int oo=0;oo<4;++oo){
    float s1=0.f, s2=0.f;
    #pragma unroll
    for (int j=0;j<4;++j){ float v=acc[oo][j]; s1+=v; s2+=v*v; }
    red[((ob+oo)*16 + qt)*2+0] = s1;
    red[((ob+oo)*16 + qt)*2+1] = s2;
  }
  __syncthreads();
  if (tid < 64){
    float s1=0.f, s2=0.f;
    #pragma unroll
    for (int k=0;k<16;++k){ s1 += red[(tid*16+k)*2]; s2 += red[(tid*16+k)*2+1]; }
    part[(size_t)bid*128 + tid*2]   = s1;
    part[(size_t)bid*128 + tid*2+1] = s2;
  }
  if (rs == 0){
    #pragma unroll
    for (int oo=0;oo<4;++oo){
      float4 v = make_float4(acc[oo][0],acc[oo][1],acc[oo][2],acc[oo][3]);
      *(float4*)(y00 + ((size_t)(n*64+ob+oo)*128 + p)*256 + q0 + qt*4) = v;
    }
  }
}

// ---------------- instance-norm statistics ----------------
__global__ __launch_bounds__(256) void k_stats(const float* __restrict__ part, float* __restrict__ stats){
  int n = blockIdx.x >> 6, o = blockIdx.x & 63;
  double s1=0.0, s2=0.0;
  for (int t = threadIdx.x; t < 2048; t += 256){
    int rs = t >> 9; int rem = t & 511; int p = rem >> 2; int qt = rem & 3;
    size_t bid = ((size_t)((rs*10+n)*128+p)*4+qt);
    s1 += (double)part[bid*128 + o*2];
    s2 += (double)part[bid*128 + o*2+1];
  }
  __shared__ double r1[256], r2[256];
  r1[threadIdx.x]=s1; r2[threadIdx.x]=s2; __syncthreads();
  for (int st=128; st>0; st>>=1){
    if (threadIdx.x<st){ r1[threadIdx.x]+=r1[threadIdx.x+st]; r2[threadIdx.x]+=r2[threadIdx.x+st]; }
    __syncthreads();
  }
  if (threadIdx.x==0){
    double mu  = r1[0] / 131072.0;
    double var = r2[0] / 131072.0 - mu*mu;
    stats[blockIdx.x*2]   = (float)mu;
    stats[blockIdx.x*2+1] = (float)(1.0/sqrt(var + 1e-5));
  }
}

__global__ __launch_bounds__(256) void k_normgelu(float* __restrict__ x, const float* __restrict__ stats){
  size_t idx = (size_t)blockIdx.x*256 + threadIdx.x;
  int no = (int)(idx >> 15);
  float mu = stats[no*2], istd = stats[no*2+1];
  float v = (x[idx]-mu)*istd;
  x[idx] = gelu_f(v);
}

// ---------------- forward DFT along W (16 modes), in-register rotation ----------------
// Cy[row][y][2], row = (n*64+e)*128 + h
__global__ __launch_bounds__(256) void k_dftW(const float* __restrict__ x, float* __restrict__ Cy){
  __shared__ float XS[32*257];
  int tid = threadIdx.x;
  size_t row0 = (size_t)blockIdx.x * 32;
  for (int t=tid; t<8192; t+=256){
    int rr = t>>8, c = t&255;
    XS[rr*257 + c] = x[(row0+rr)*256 + c];
  }
  __syncthreads();
  int y = tid & 15, rg = tid >> 4;
  double ad = -2.0*PI_D*(double)y/256.0;
  float stc = (float)cos(ad), sts = (float)sin(ad);
  float rr_=1.f, ri_=0.f;
  float a0r=0.f,a0i=0.f,a1r=0.f,a1i=0.f;
  const float* xr0 = XS + (rg*2)*257;
  const float* xr1 = xr0 + 257;
  for (int w=0; w<256; ++w){
    float x0 = xr0[w], x1 = xr1[w];
    a0r += x0*rr_; a0i += x0*ri_;
    a1r += x1*rr_; a1i += x1*ri_;
    float nr = rr_*stc - ri_*sts;
    ri_ = rr_*sts + ri_*stc;
    rr_ = nr;
  }
  size_t r0 = row0 + rg*2;
  *(float2*)(Cy + (r0*16 + y)*2)     = make_float2(a0r, a0i);
  *(float2*)(Cy + ((r0+1)*16 + y)*2) = make_float2(a1r, a1i);
}

// ---------------- forward DFT along H (32 modes) ----------------
// coeff[n][e][m][y][2]; block per (n,e)
__global__ __launch_bounds__(256) void k_dftH(const float* __restrict__ Cy, const float* __restrict__ twg,
                                              float* __restrict__ coeff){
  __shared__ float CS[128*32];   // [h][y][2]
  __shared__ float TW[128*64];   // [h][m][2]
  int tid = threadIdx.x;
  size_t base = (size_t)blockIdx.x * 4096;
  for (int t=tid; t<4096; t+=256) CS[t] = Cy[base + t];
  for (int t=tid; t<8192; t+=256) TW[t] = twg[t];
  __syncthreads();
  int m = tid >> 3, yg = tid & 7;
  float c0r=0.f,c0i=0.f,c1r=0.f,c1i=0.f;
  for (int h=0; h<128; ++h){
    float2 tw = *(const float2*)(TW + h*64 + m*2);
    float2 v0 = *(const float2*)(CS + h*32 + yg*4);
    float2 v1 = *(const float2*)(CS + h*32 + yg*4 + 2);
    c0r += v0.x*tw.x - v0.y*tw.y;
    c0i += v0.x*tw.y + v0.y*tw.x;
    c1r += v1.x*tw.x - v1.y*tw.y;
    c1i += v1.x*tw.y + v1.y*tw.x;
  }
  size_t ob = (size_t)blockIdx.x*1024 + m*32 + yg*4;
  *(float2*)(coeff+ob)   = make_float2(c0r,c0i);
  *(float2*)(coeff+ob+2) = make_float2(c1r,c1i);
}

// ---------------- spectral mode mixing ----------------
// blockIdx.x = (m*4 + oq)*2 + ng ; mo[n][o][m][y][2]
__global__ __launch_bounds__(256) void k_modemix(const float* __restrict__ coeff,
                                                 const float* __restrict__ wr, const float* __restrict__ wi,
                                                 float* __restrict__ mo){
  __shared__ float CS[5*64*32]; // [nn][i][y][2]
  int bid = blockIdx.x;
  int ng = bid & 1;
  int oq = (bid >> 1) & 3;
  int m  = bid >> 3;
  int blk = m >> 4, mm = m & 15;
  int n0 = ng*5;
  int tid = threadIdx.x;
  for (int t=tid; t<2560; t+=256){
    int ni = t >> 3, prt = t & 7;
    int nn = ni >> 6, i = ni & 63;
    *(float4*)(CS + (nn*64+i)*32 + prt*4) =
      *(const float4*)(coeff + ((size_t)((n0+nn)*64+i)*32 + m)*32 + prt*4);
  }
  __syncthreads();
  int ty = tid >> 4, y = tid & 15;
  int o = oq*16 + ty;
  float ar[5], ai[5];
  #pragma unroll
  for (int nn=0;nn<5;++nn){ ar[nn]=0.f; ai[nn]=0.f; }
  const float* wrb = wr + ((size_t)(blk*64)*64 + o)*256 + mm*16 + y;
  const float* wib = wi + ((size_t)(blk*64)*64 + o)*256 + mm*16 + y;
  for (int i=0;i<64;++i){
    float wrv = wrb[(size_t)i*16384];
    float wiv = wib[(size_t)i*16384];
    const float* cp = CS + i*32 + y*2;
    #pragma unroll
    for (int nn=0;nn<5;++nn){
      float2 c2 = *(const float2*)(cp + nn*2048);
      ar[nn] += c2.x*wrv - c2.y*wiv;
      ai[nn] += c2.x*wiv + c2.y*wrv;
    }
  }
  #pragma unroll
  for (int nn=0;nn<5;++nn)
    *(float2*)(mo + (((size_t)((n0+nn)*64+o)*32 + m)*16 + y)*2) = make_float2(ar[nn], ai[nn]);
}

// ---------------- inverse DFT along H ----------------
// G[n][o][h][y][2], alpha_y/32768 folded in; block per (n,o)
__global__ __launch_bounds__(256) void k_idftH(const float* __restrict__ mo, const float* __restrict__ twg,
                                               float* __restrict__ G){
  __shared__ float MS[1024];     // [m][y][2]
  __shared__ float TW[8192];     // [m][h][2]
  int tid = threadIdx.x;
  size_t base = (size_t)blockIdx.x * 1024;
  for (int t=tid; t<1024; t+=256) MS[t] = mo[base + t];
  for (int t=tid; t<8192; t+=256) TW[t] = twg[t];
  __syncthreads();
  int y = tid & 15, hg = tid >> 4;
  float gr[8], gi[8];
  #pragma unroll
  for (int k=0;k<8;++k){ gr[k]=0.f; gi[k]=0.f; }
  for (int mI=0;mI<32;++mI){
    float2 c = *(const float2*)(MS + mI*32 + y*2);
    const float* twp = TW + mI*256 + hg*16;
    #pragma unroll
    for (int k=0;k<8;++k){
      float2 tw = *(const float2*)(twp + k*2);
      gr[k] += c.x*tw.x - c.y*tw.y;
      gi[k] += c.x*tw.y + c.y*tw.x;
    }
  }
  float f = (y==0) ? (1.f/32768.f) : (2.f/32768.f);
  #pragma unroll
  for (int k=0;k<8;++k){
    int h = hg*8+k;
    *(float2*)(G + ((size_t)blockIdx.x*128 + h)*32 + y*2) = make_float2(gr[k]*f, gi[k]*f);
  }
}

// ---------------- inverse DFT along W + 1x1 skip + gelu ----------------
// blockIdx.x = (n*128 + h)*2 + wh
__global__ __launch_bounds__(256) void k_combine(const float* __restrict__ xa, const float* __restrict__ G,
                                                 const float* __restrict__ twg, const float* __restrict__ cw,
                                                 const float* __restrict__ cb, float* __restrict__ xb){
  __shared__ float XT[64*128];   // [i][w]
  __shared__ float GS[64*32];    // [o][y][2]
  int bid = blockIdx.x;
  int wh = bid & 1; int h = (bid>>1)&127; int n = bid>>8;
  int w0 = wh*128;
  int tid = threadIdx.x;
  for (int t=tid; t<8192; t+=256){
    int i = t>>7, w = t&127;
    XT[t] = xa[((size_t)(n*64+i)*128 + h)*256 + w0 + w];
  }
  for (int t=tid; t<2048; t+=256){
    int o = t>>5, j = t&31;
    GS[t] = G[((size_t)(n*64+o)*128 + h)*32 + j];
  }
  __syncthreads();
  int wg = tid & 31, og = tid >> 5;
  float acc[8][4];
  #pragma unroll
  for (int k=0;k<8;++k){
    float b = cb[og*8+k];
    #pragma unroll
    for (int j=0;j<4;++j) acc[k][j]=b;
  }
  for (int i=0;i<64;++i){
    float4 xv = *(const float4*)(XT + i*128 + wg*4);
    #pragma unroll
    for (int k=0;k<8;++k){
      float wv = cw[(og*8+k)*64 + i];
      acc[k][0] += wv*xv.x; acc[k][1] += wv*xv.y;
      acc[k][2] += wv*xv.z; acc[k][3] += wv*xv.w;
    }
  }
  // spectral: rot_y(w) = e^{+2pi i w y/256} by per-w rotation
  float sr[4], si[4], rr[4], ri[4];
  #pragma unroll
  for (int j=0;j<4;++j){
    int w = w0 + wg*4 + j;
    float2 st = *(const float2*)(twg + w*32 + 2);  // y=1 entry
    sr[j]=st.x; si[j]=st.y; rr[j]=1.f; ri[j]=0.f;
  }
  #pragma unroll
  for (int k=0;k<8;++k){
    float g0 = GS[(og*8+k)*32];
    #pragma unroll
    for (int j=0;j<4;++j) acc[k][j] += g0;
  }
  for (int y=1;y<16;++y){
    #pragma unroll
    for (int j=0;j<4;++j){
      float nr = rr[j]*sr[j] - ri[j]*si[j];
      ri[j] = rr[j]*si[j] + ri[j]*sr[j];
      rr[j] = nr;
    }
    #pragma unroll
    for (int k=0;k<8;++k){
      float2 g = *(const float2*)(GS + (og*8+k)*32 + y*2);
      #pragma unroll
      for (int j=0;j<4;++j)
        acc[k][j] += g.x*rr[j] - g.y*ri[j];
    }
  }
  #pragma unroll
  for (int k=0;k<8;++k){
    int o = og*8+k;
    float4 r;
    r.x = gelu_f(acc[k][0]); r.y = gelu_f(acc[k][1]);
    r.z = gelu_f(acc[k][2]); r.w = gelu_f(acc[k][3]);
    *(float4*)(xb + ((size_t)(n*64+o)*128 + h)*256 + w0 + wg*4) = r;
  }
}

// ---------------- downdim 1x1 conv (E=64 -> C=2) ----------------
__global__ __launch_bounds__(256) void k_downdim(const float* __restrict__ x, const float* __restrict__ wd,
                                                 const float* __restrict__ bd, float* __restrict__ out){
  size_t idx = (size_t)blockIdx.x*256 + threadIdx.x;  // over 10*32768
  int n = (int)(idx >> 15);
  int pos = (int)(idx & 32767);
  float a0 = bd[0], a1 = bd[1];
  const float* xp = x + (size_t)n*64*32768 + pos;
  for (int e=0;e<64;++e){
    float v = xp[(size_t)e*32768];
    a0 += wd[e]*v;
    a1 += wd[64+e]*v;
  }
  out[(size_t)n*65536 + pos] = a0;
  out[(size_t)n*65536 + 32768 + pos] = a1;
}

extern "C" void kernel_launch(void* const* d_in, const int* in_sizes, int n_in,
                              void* d_out, int out_size, void* d_ws, size_t ws_size,
                              hipStream_t stream) {
  const float* sv  = (const float*)d_in[0];
  const float* upw = (const float*)d_in[1];
  const float* upb = (const float*)d_in[2];
  const float* smw = (const float*)d_in[3];
  const float* smb = (const float*)d_in[4];
  const float* fwr = (const float*)d_in[5];
  const float* fwi = (const float*)d_in[6];
  const float* fcw = (const float*)d_in[7];
  const float* fcb = (const float*)d_in[8];
  const float* ddw = (const float*)d_in[9];
  const float* ddb = (const float*)d_in[10];
  float* out = (float*)d_out;

  float* W = (float*)d_ws;
  float* bufA  = W;                       // 20971520
  float* bufU  = W + 20971520;            // 20971520 (reused as FNO ping buffer)
  float* small = W + 41943040;            // 6553600
  float* Cy    = small;                   // 2621440
  float* G     = small + 2621440;         // 2621440
  float* coeff = small + 5242880;         // 655360
  float* mo    = small + 5898240;         // 655360
  float* part  = small;                   // aliases Cy (conv phase only)
  float* stats = W + 48496640;            // 1280
  float* K     = stats + 1280;            // 65536
  float* twFwW = K + 65536;               // 8192
  float* twFwH = twFwW + 8192;            // 8192
  float* twBwH = twFwH + 8192;            // 8192
  float* twBwW = twBwH + 8192;            // 8192

  k_tables<<<64,256,0,stream>>>(twFwW, twFwH, twBwH, twBwW);
  k_buildK<<<16,256,0,stream>>>(smw, K);
  k_updim<<<81920,256,0,stream>>>(sv, upw, upb, bufU);
  k_conv<<<20480,256,0,stream>>>(bufU, K, smb, bufA, part);
  k_stats<<<640,256,0,stream>>>(part, stats);
  k_normgelu<<<81920,256,0,stream>>>(bufA, stats);

  float* xa = bufA; float* xb = bufU;
  for (int l=0;l<4;++l){
    k_dftW<<<2560,256,0,stream>>>(xa, Cy);
    k_dftH<<<640,256,0,stream>>>(Cy, twFwH, coeff);
    k_modemix<<<256,256,0,stream>>>(coeff, fwr + (size_t)l*2097152, fwi + (size_t)l*2097152, mo);
    k_idftH<<<640,256,0,stream>>>(mo, twBwH, G);
    k_combine<<<2560,256,0,stream>>>(xa, G, twBwW, fcw + (size_t)l*4096, fcb + (size_t)l*64, xb);
    float* t = xa; xa = xb; xb = t;
  }
  k_downdim<<<1280,256,0,stream>>>(xa, ddw, ddb, out);
}

// Round 2
// 1437.022 us; speedup vs baseline: 1.4714x; 1.4714x over previous
//
#include <hip/hip_runtime.h>
#include <math.h>

#define PI_D 3.14159265358979323846

// N=10 images, E=64 ch, H=128, W=256, M=16 modes, L=4 layers

typedef _Float16 h8 __attribute__((ext_vector_type(8)));
typedef float f16v __attribute__((ext_vector_type(16)));

__device__ __forceinline__ float gelu_f(float v){
  return 0.5f*v*(1.0f + erff(v*0.70710678118654752440f));
}

// ---------------- twiddle tables ----------------
__global__ __launch_bounds__(256) void k_tables(float* __restrict__ twFwW, float* __restrict__ twFwH,
                                                float* __restrict__ twBwH, float* __restrict__ twBwW){
  int id = blockIdx.x*256 + threadIdx.x;
  int tab = id >> 12, j = id & 4095;
  if (tab == 0){
    int w = j >> 4, y = j & 15;
    double ang = -2.0*PI_D*(double)((y*w) & 255)/256.0;
    twFwW[j*2]   = (float)cos(ang);
    twFwW[j*2+1] = (float)sin(ang);
  } else if (tab == 1){
    int m = j & 31;
    int h = j >> 5;
    int xm = (m < 16) ? m : (96 + m);
    double ang = -2.0*PI_D*(double)((xm*h) & 127)/128.0;
    twFwH[j*2]   = (float)cos(ang);
    twFwH[j*2+1] = (float)sin(ang);
  } else if (tab == 2){
    int m = j >> 7, h = j & 127;
    int xm = (m < 16) ? m : (96 + m);
    double ang = 2.0*PI_D*(double)((xm*h) & 127)/128.0;
    twBwH[j*2]   = (float)cos(ang);
    twBwH[j*2+1] = (float)sin(ang);
  } else {
    int w = j >> 4, y = j & 15;
    double ang = 2.0*PI_D*(double)((y*w) & 255)/256.0;
    twBwW[j*2]   = (float)cos(ang);
    twBwW[j*2+1] = (float)sin(ang);
  }
}

// ---------------- collapsed 2x2 conv kernels -> fp16, layout [rs][tap][o][i] ----------------
__global__ __launch_bounds__(256) void k_buildK(const float* __restrict__ w, _Float16* __restrict__ K4h){
  int id = blockIdx.x*256 + threadIdx.x; // 0..4095 = o*64+i
  int o = id >> 6, i = id & 63;
  float w9[9];
  #pragma unroll
  for (int k=0;k<9;++k) w9[k] = w[id*9 + k];
  #pragma unroll
  for (int r=0;r<2;++r){
    #pragma unroll
    for (int s=0;s<2;++s){
      int rs = r*2+s;
      #pragma unroll
      for (int a=0;a<2;++a){
        int klo = (r==0) ? (a==0?0:1) : (a==0?0:2);
        int khi = (r==0) ? (a==0?0:2) : (a==0?1:2);
        #pragma unroll
        for (int b=0;b<2;++b){
          int llo = (s==0) ? (b==0?0:1) : (b==0?0:2);
          int lhi = (s==0) ? (b==0?0:2) : (b==0?1:2);
          float sum = 0.f;
          for (int kh=klo; kh<=khi; ++kh)
            for (int kw=llo; kw<=lhi; ++kw)
              sum += w9[kh*3+kw];
          K4h[((size_t)((rs*4) + a*2+b)*64 + o)*64 + i] = (_Float16)sum;
        }
      }
    }
  }
}

// ---------------- updim 1x1 conv (C=2 -> E=64) ----------------
__global__ __launch_bounds__(256) void k_updim(const float* __restrict__ sv, const float* __restrict__ w,
                                               const float* __restrict__ b, float* __restrict__ u){
  size_t idx = (size_t)blockIdx.x*256 + threadIdx.x;
  int pos = (int)(idx & 32767);
  int e   = (int)((idx >> 15) & 63);
  int n   = (int)(idx >> 21);
  float v0 = sv[(size_t)n*65536 + pos];
  float v1 = sv[(size_t)n*65536 + 32768 + pos];
  u[idx] = w[e*2+0]*v0 + w[e*2+1]*v1 + b[e];
}

// ---------------- MFMA collapsed conv, all 4 parities per block ----------------
// blocks: n(10) * pg(32) * qt4(4) = 1280, 512 threads = 8 waves = (otile 2) x (rs 4)
// LDS strip: rows p0-1..p0+4 (6), cols q0-1..q0+64 (66), 64 in-ch fp16,
// XOR-swizzled: addr_half(row,c,i) = ((row*66+c)<<6) + (((c + (i>>3))&7)<<3) + (i&7)
__global__ __launch_bounds__(512, 2) void k_conv_mfma(const float* __restrict__ u,
                                                      const _Float16* __restrict__ K4h,
                                                      const float* __restrict__ sb,
                                                      float* __restrict__ y00,
                                                      float* __restrict__ part){
  __shared__ _Float16 Xs[25344]; // 6*66*64
  const int tid = threadIdx.x;
  int bid = blockIdx.x;
  int qt4 = bid & 3;
  int pg  = (bid >> 2) & 31;
  int n   = bid >> 7;
  int p0 = pg*4, q0 = qt4*64;

  // -------- staging: u fp32 -> fp16 swizzled LDS --------
  for (int idx = tid; idx < 18432; idx += 512){
    int c5  = idx & 31;
    int ip1 = (idx >> 5) & 1;
    int iphi= (idx >> 6) & 15;
    int t3  = idx >> 10;      // 0..17
    int chi = t3 % 3;
    int row = t3 / 3;
    int c = chi*32 + c5;
    if (c < 66){
      int i = iphi*4 + ip1*2;
      int grow = p0 - 1 + row;
      int gcol = q0 - 1 + c;
      float v0 = 0.f, v1 = 0.f;
      if (grow >= 0 && grow < 128 && gcol >= 0 && gcol < 256){
        const float* up = u + ((size_t)(n*64 + i)*128 + grow)*256 + gcol;
        v0 = up[0]; v1 = up[32768];
      }
      int g = i >> 3;
      int addr = ((row*66 + c) << 6) + (((c + g) & 7) << 3) + (i & 7);
      union { _Float16 h[2]; unsigned int u32; } pk;
      pk.h[0] = (_Float16)v0; pk.h[1] = (_Float16)v1;
      *(unsigned int*)(Xs + addr) = pk.u32;
    }
  }
  __syncthreads();

  // -------- per-wave role --------
  int wid  = tid >> 6;
  int lane = tid & 63;
  int rs = wid & 3;
  int ot = wid >> 2;
  int r = rs >> 1, s = rs & 1;
  int l31 = lane & 31;
  int l5  = lane >> 5;

  // A fragments in registers: [tap][kstep]
  h8 af[4][4];
  {
    const _Float16* kb = K4h + ((size_t)(rs*4)*64 + ot*32 + l31)*64 + l5*8;
    #pragma unroll
    for (int tap=0;tap<4;++tap)
      #pragma unroll
      for (int ks=0;ks<4;++ks)
        af[tap][ks] = *(const h8*)(kb + (size_t)tap*4096 + ks*16);
  }
  float bias_j[16];
  #pragma unroll
  for (int j=0;j<16;++j) bias_j[j] = sb[ot*32 + (j&3) + 8*(j>>2) + 4*l5];

  float s1[16], s2[16];
  #pragma unroll
  for (int j=0;j<16;++j){ s1[j]=0.f; s2[j]=0.f; }

  for (int dp=0; dp<4; ++dp){
    f16v acc0, acc1;
    #pragma unroll
    for (int j=0;j<16;++j){ acc0[j] = bias_j[j]; acc1[j] = bias_j[j]; }
    #pragma unroll
    for (int tap=0;tap<4;++tap){
      int a = tap >> 1, b = tap & 1;
      int row = dp + a + r;                 // strip row index
      int rowbase = (row*66) << 6;
      {
        int c = l31 + s + b;                // qt2 = 0
        int cb = rowbase + (c << 6);
        #pragma unroll
        for (int ks=0;ks<4;++ks){
          int addr = cb + (((c + ks*2 + l5) & 7) << 3);
          h8 bf = *(const h8*)(Xs + addr);
          acc0 = __builtin_amdgcn_mfma_f32_32x32x16_f16(af[tap][ks], bf, acc0, 0,0,0);
        }
      }
      {
        int c = 32 + l31 + s + b;           // qt2 = 1
        int cb = rowbase + (c << 6);
        #pragma unroll
        for (int ks=0;ks<4;++ks){
          int addr = cb + (((c + ks*2 + l5) & 7) << 3);
          h8 bf = *(const h8*)(Xs + addr);
          acc1 = __builtin_amdgcn_mfma_f32_32x32x16_f16(af[tap][ks], bf, acc1, 0,0,0);
        }
      }
    }
    // stats accumulation (reg j -> fixed o)
    #pragma unroll
    for (int j=0;j<16;++j){
      float v0 = acc0[j], v1 = acc1[j];
      s1[j] += v0 + v1;
      s2[j] += v0*v0 + v1*v1;
    }
    // store parity (0,0) output
    if (rs == 0){
      int p = p0 + dp;
      #pragma unroll
      for (int j=0;j<16;++j){
        int o = ot*32 + (j&3) + 8*(j>>2) + 4*l5;
        float* yp = y00 + ((size_t)(n*64+o)*128 + p)*256 + q0 + l31;
        yp[0]  = acc0[j];
        yp[32] = acc1[j];
      }
    }
  }

  // -------- cross-lane stats reduction (within 32-lane halves) --------
  #pragma unroll
  for (int m=1;m<=16;m<<=1){
    #pragma unroll
    for (int j=0;j<16;++j){
      s1[j] += __shfl_xor(s1[j], m, 64);
      s2[j] += __shfl_xor(s2[j], m, 64);
    }
  }
  if (l31 == 0){
    float* pp = part + ((size_t)bid*4 + rs)*128;
    #pragma unroll
    for (int j=0;j<16;++j){
      int o = ot*32 + (j&3) + 8*(j>>2) + 4*l5;
      pp[o*2]   = s1[j];
      pp[o*2+1] = s2[j];
    }
  }
}

// ---------------- instance-norm statistics reduce ----------------
__global__ __launch_bounds__(256) void k_stats2(const float* __restrict__ part, float* __restrict__ stats){
  int n = blockIdx.x >> 6, o = blockIdx.x & 63;
  double a1=0.0, a2=0.0;
  #pragma unroll
  for (int it=0; it<2; ++it){
    int idx = threadIdx.x + it*256;   // pg*16 + qt4*4 + rs
    int pg = idx >> 4, qt4 = (idx>>2)&3, rs = idx&3;
    int bid = (n*32 + pg)*4 + qt4;
    a1 += (double)part[((size_t)bid*4 + rs)*128 + o*2];
    a2 += (double)part[((size_t)bid*4 + rs)*128 + o*2+1];
  }
  __shared__ double r1[256], r2[256];
  r1[threadIdx.x]=a1; r2[threadIdx.x]=a2; __syncthreads();
  for (int st=128; st>0; st>>=1){
    if (threadIdx.x<st){ r1[threadIdx.x]+=r1[threadIdx.x+st]; r2[threadIdx.x]+=r2[threadIdx.x+st]; }
    __syncthreads();
  }
  if (threadIdx.x==0){
    double mu  = r1[0] / 131072.0;
    double var = r2[0] / 131072.0 - mu*mu;
    stats[blockIdx.x*2]   = (float)mu;
    stats[blockIdx.x*2+1] = (float)(1.0/sqrt(var + 1e-5));
  }
}

__global__ __launch_bounds__(256) void k_normgelu(float* __restrict__ x, const float* __restrict__ stats){
  size_t idx = (size_t)blockIdx.x*256 + threadIdx.x;
  int no = (int)(idx >> 15);
  float mu = stats[no*2], istd = stats[no*2+1];
  float v = (x[idx]-mu)*istd;
  x[idx] = gelu_f(v);
}

// ---------------- forward DFT along W (16 modes) ----------------
__global__ __launch_bounds__(256) void k_dftW(const float* __restrict__ x, float* __restrict__ Cy){
  __shared__ float XS[32*257];
  int tid = threadIdx.x;
  size_t row0 = (size_t)blockIdx.x * 32;
  for (int t=tid; t<8192; t+=256){
    int rr = t>>8, c = t&255;
    XS[rr*257 + c] = x[(row0+rr)*256 + c];
  }
  __syncthreads();
  int y = tid & 15, rg = tid >> 4;
  double ad = -2.0*PI_D*(double)y/256.0;
  float stc = (float)cos(ad), sts = (float)sin(ad);
  float rr_=1.f, ri_=0.f;
  float a0r=0.f,a0i=0.f,a1r=0.f,a1i=0.f;
  const float* xr0 = XS + (rg*2)*257;
  const float* xr1 = xr0 + 257;
  for (int w=0; w<256; ++w){
    float x0 = xr0[w], x1 = xr1[w];
    a0r += x0*rr_; a0i += x0*ri_;
    a1r += x1*rr_; a1i += x1*ri_;
    float nr = rr_*stc - ri_*sts;
    ri_ = rr_*sts + ri_*stc;
    rr_ = nr;
  }
  size_t r0 = row0 + rg*2;
  *(float2*)(Cy + (r0*16 + y)*2)     = make_float2(a0r, a0i);
  *(float2*)(Cy + ((r0+1)*16 + y)*2) = make_float2(a1r, a1i);
}

// ---------------- forward DFT along H (32 modes) ----------------
__global__ __launch_bounds__(256) void k_dftH(const float* __restrict__ Cy, const float* __restrict__ twg,
                                              float* __restrict__ coeff){
  __shared__ float CS[128*32];
  __shared__ float TW[128*64];
  int tid = threadIdx.x;
  size_t base = (size_t)blockIdx.x * 4096;
  for (int t=tid; t<4096; t+=256) CS[t] = Cy[base + t];
  for (int t=tid; t<8192; t+=256) TW[t] = twg[t];
  __syncthreads();
  int m = tid >> 3, yg = tid & 7;
  float c0r=0.f,c0i=0.f,c1r=0.f,c1i=0.f;
  for (int h=0; h<128; ++h){
    float2 tw = *(const float2*)(TW + h*64 + m*2);
    float2 v0 = *(const float2*)(CS + h*32 + yg*4);
    float2 v1 = *(const float2*)(CS + h*32 + yg*4 + 2);
    c0r += v0.x*tw.x - v0.y*tw.y;
    c0i += v0.x*tw.y + v0.y*tw.x;
    c1r += v1.x*tw.x - v1.y*tw.y;
    c1i += v1.x*tw.y + v1.y*tw.x;
  }
  size_t ob = (size_t)blockIdx.x*1024 + m*32 + yg*4;
  *(float2*)(coeff+ob)   = make_float2(c0r,c0i);
  *(float2*)(coeff+ob+2) = make_float2(c1r,c1i);
}

// ---------------- spectral mode mixing ----------------
__global__ __launch_bounds__(256) void k_modemix(const float* __restrict__ coeff,
                                                 const float* __restrict__ wr, const float* __restrict__ wi,
                                                 float* __restrict__ mo){
  __shared__ float CS[5*64*32];
  int bid = blockIdx.x;
  int ng = bid & 1;
  int oq = (bid >> 1) & 3;
  int m  = bid >> 3;
  int blk = m >> 4, mm = m & 15;
  int n0 = ng*5;
  int tid = threadIdx.x;
  for (int t=tid; t<2560; t+=256){
    int ni = t >> 3, prt = t & 7;
    int nn = ni >> 6, i = ni & 63;
    *(float4*)(CS + (nn*64+i)*32 + prt*4) =
      *(const float4*)(coeff + ((size_t)((n0+nn)*64+i)*32 + m)*32 + prt*4);
  }
  __syncthreads();
  int ty = tid >> 4, y = tid & 15;
  int o = oq*16 + ty;
  float ar[5], ai[5];
  #pragma unroll
  for (int nn=0;nn<5;++nn){ ar[nn]=0.f; ai[nn]=0.f; }
  const float* wrb = wr + ((size_t)(blk*64)*64 + o)*256 + mm*16 + y;
  const float* wib = wi + ((size_t)(blk*64)*64 + o)*256 + mm*16 + y;
  for (int i=0;i<64;++i){
    float wrv = wrb[(size_t)i*16384];
    float wiv = wib[(size_t)i*16384];
    const float* cp = CS + i*32 + y*2;
    #pragma unroll
    for (int nn=0;nn<5;++nn){
      float2 c2 = *(const float2*)(cp + nn*2048);
      ar[nn] += c2.x*wrv - c2.y*wiv;
      ai[nn] += c2.x*wiv + c2.y*wrv;
    }
  }
  #pragma unroll
  for (int nn=0;nn<5;++nn)
    *(float2*)(mo + (((size_t)((n0+nn)*64+o)*32 + m)*16 + y)*2) = make_float2(ar[nn], ai[nn]);
}

// ---------------- inverse DFT along H ----------------
__global__ __launch_bounds__(256) void k_idftH(const float* __restrict__ mo, const float* __restrict__ twg,
                                               float* __restrict__ G){
  __shared__ float MS[1024];
  __shared__ float TW[8192];
  int tid = threadIdx.x;
  size_t base = (size_t)blockIdx.x * 1024;
  for (int t=tid; t<1024; t+=256) MS[t] = mo[base + t];
  for (int t=tid; t<8192; t+=256) TW[t] = twg[t];
  __syncthreads();
  int y = tid & 15, hg = tid >> 4;
  float gr[8], gi[8];
  #pragma unroll
  for (int k=0;k<8;++k){ gr[k]=0.f; gi[k]=0.f; }
  for (int mI=0;mI<32;++mI){
    float2 c = *(const float2*)(MS + mI*32 + y*2);
    const float* twp = TW + mI*256 + hg*16;
    #pragma unroll
    for (int k=0;k<8;++k){
      float2 tw = *(const float2*)(twp + k*2);
      gr[k] += c.x*tw.x - c.y*tw.y;
      gi[k] += c.x*tw.y + c.y*tw.x;
    }
  }
  float f = (y==0) ? (1.f/32768.f) : (2.f/32768.f);
  #pragma unroll
  for (int k=0;k<8;++k){
    int h = hg*8+k;
    *(float2*)(G + ((size_t)blockIdx.x*128 + h)*32 + y*2) = make_float2(gr[k]*f, gi[k]*f);
  }
}

// ---------------- inverse DFT along W + 1x1 skip + gelu ----------------
__global__ __launch_bounds__(256) void k_combine(const float* __restrict__ xa, const float* __restrict__ G,
                                                 const float* __restrict__ twg, const float* __restrict__ cw,
                                                 const float* __restrict__ cb, float* __restrict__ xb){
  __shared__ float XT[64*128];
  __shared__ float GS[64*32];
  int bid = blockIdx.x;
  int wh = bid & 1; int h = (bid>>1)&127; int n = bid>>8;
  int w0 = wh*128;
  int tid = threadIdx.x;
  for (int t=tid; t<8192; t+=256){
    int i = t>>7, w = t&127;
    XT[t] = xa[((size_t)(n*64+i)*128 + h)*256 + w0 + w];
  }
  for (int t=tid; t<2048; t+=256){
    int o = t>>5, j = t&31;
    GS[t] = G[((size_t)(n*64+o)*128 + h)*32 + j];
  }
  __syncthreads();
  int wg = tid & 31, og = tid >> 5;
  float acc[8][4];
  #pragma unroll
  for (int k=0;k<8;++k){
    float b = cb[og*8+k];
    #pragma unroll
    for (int j=0;j<4;++j) acc[k][j]=b;
  }
  for (int i=0;i<64;++i){
    float4 xv = *(const float4*)(XT + i*128 + wg*4);
    #pragma unroll
    for (int k=0;k<8;++k){
      float wv = cw[(og*8+k)*64 + i];
      acc[k][0] += wv*xv.x; acc[k][1] += wv*xv.y;
      acc[k][2] += wv*xv.z; acc[k][3] += wv*xv.w;
    }
  }
  float sr[4], si[4], rr[4], ri[4];
  #pragma unroll
  for (int j=0;j<4;++j){
    int w = w0 + wg*4 + j;
    float2 st = *(const float2*)(twg + w*32 + 2);
    sr[j]=st.x; si[j]=st.y; rr[j]=1.f; ri[j]=0.f;
  }
  #pragma unroll
  for (int k=0;k<8;++k){
    float g0 = GS[(og*8+k)*32];
    #pragma unroll
    for (int j=0;j<4;++j) acc[k][j] += g0;
  }
  for (int y=1;y<16;++y){
    #pragma unroll
    for (int j=0;j<4;++j){
      float nr = rr[j]*sr[j] - ri[j]*si[j];
      ri[j] = rr[j]*si[j] + ri[j]*sr[j];
      rr[j] = nr;
    }
    #pragma unroll
    for (int k=0;k<8;++k){
      float2 g = *(const float2*)(GS + (og*8+k)*32 + y*2);
      #pragma unroll
      for (int j=0;j<4;++j)
        acc[k][j] += g.x*rr[j] - g.y*ri[j];
    }
  }
  #pragma unroll
  for (int k=0;k<8;++k){
    int o = og*8+k;
    float4 r;
    r.x = gelu_f(acc[k][0]); r.y = gelu_f(acc[k][1]);
    r.z = gelu_f(acc[k][2]); r.w = gelu_f(acc[k][3]);
    *(float4*)(xb + ((size_t)(n*64+o)*128 + h)*256 + w0 + wg*4) = r;
  }
}

// ---------------- downdim 1x1 conv (E=64 -> C=2) ----------------
__global__ __launch_bounds__(256) void k_downdim(const float* __restrict__ x, const float* __restrict__ wd,
                                                 const float* __restrict__ bd, float* __restrict__ out){
  size_t idx = (size_t)blockIdx.x*256 + threadIdx.x;
  int n = (int)(idx >> 15);
  int pos = (int)(idx & 32767);
  float a0 = bd[0], a1 = bd[1];
  const float* xp = x + (size_t)n*64*32768 + pos;
  for (int e=0;e<64;++e){
    float v = xp[(size_t)e*32768];
    a0 += wd[e]*v;
    a1 += wd[64+e]*v;
  }
  out[(size_t)n*65536 + pos] = a0;
  out[(size_t)n*65536 + 32768 + pos] = a1;
}

extern "C" void kernel_launch(void* const* d_in, const int* in_sizes, int n_in,
                              void* d_out, int out_size, void* d_ws, size_t ws_size,
                              hipStream_t stream) {
  const float* sv  = (const float*)d_in[0];
  const float* upw = (const float*)d_in[1];
  const float* upb = (const float*)d_in[2];
  const float* smw = (const float*)d_in[3];
  const float* smb = (const float*)d_in[4];
  const float* fwr = (const float*)d_in[5];
  const float* fwi = (const float*)d_in[6];
  const float* fcw = (const float*)d_in[7];
  const float* fcb = (const float*)d_in[8];
  const float* ddw = (const float*)d_in[9];
  const float* ddb = (const float*)d_in[10];
  float* out = (float*)d_out;

  float* W = (float*)d_ws;
  float* bufA  = W;                       // 20971520
  float* bufU  = W + 20971520;            // 20971520
  float* small = W + 41943040;            // 6553600
  float* Cy    = small;                   // 2621440
  float* G     = small + 2621440;         // 2621440
  float* coeff = small + 5242880;         // 655360
  float* mo    = small + 5898240;         // 655360
  float* part  = small;                   // aliases Cy (conv phase only), 655360 used
  float* stats = W + 48496640;            // 1280
  _Float16* K4h = (_Float16*)(stats + 1280); // 65536 halfs in 65536-float region
  float* Kreg  = stats + 1280;
  float* twFwW = Kreg + 65536;            // 8192
  float* twFwH = twFwW + 8192;            // 8192
  float* twBwH = twFwH + 8192;            // 8192
  float* twBwW = twBwH + 8192;            // 8192

  k_tables<<<64,256,0,stream>>>(twFwW, twFwH, twBwH, twBwW);
  k_buildK<<<16,256,0,stream>>>(smw, K4h);
  k_updim<<<81920,256,0,stream>>>(sv, upw, upb, bufU);
  k_conv_mfma<<<1280,512,0,stream>>>(bufU, K4h, smb, bufA, part);
  k_stats2<<<640,256,0,stream>>>(part, stats);
  k_normgelu<<<81920,256,0,stream>>>(bufA, stats);

  float* xa = bufA; float* xb = bufU;
  for (int l=0;l<4;++l){
    k_dftW<<<2560,256,0,stream>>>(xa, Cy);
    k_dftH<<<640,256,0,stream>>>(Cy, twFwH, coeff);
    k_modemix<<<256,256,0,stream>>>(coeff, fwr + (size_t)l*2097152, fwi + (size_t)l*2097152, mo);
    k_idftH<<<640,256,0,stream>>>(mo, twBwH, G);
    k_combine<<<2560,256,0,stream>>>(xa, G, twBwW, fcw + (size_t)l*4096, fcb + (size_t)l*64, xb);
    float* t = xa; xa = xb; xb = t;
  }
  k_downdim<<<1280,256,0,stream>>>(xa, ddw, ddb, out);
}

// Round 3
// 700.883 us; speedup vs baseline: 3.0167x; 2.0503x over previous
//
#include <hip/hip_runtime.h>
#include <math.h>

#define PI_D 3.14159265358979323846

// N=10 images, E=64 ch, H=128, W=256, M=16 modes, L=4 layers

typedef _Float16 h8 __attribute__((ext_vector_type(8)));
typedef _Float16 h4v __attribute__((ext_vector_type(4)));
typedef float f16v __attribute__((ext_vector_type(16)));

__device__ __forceinline__ float gelu_f(float v){
  return 0.5f*v*(1.0f + erff(v*0.70710678118654752440f));
}

// ---------------- tables ----------------
// twFwH: [h 128][m 32][2]  e^{-2pi i x_m h /128}
// twBwH: [m 32][h 128][2]  e^{+2pi i x_m h /128}
// Tspec (fp16): [w 256][kk 32], kk=2y+c: c0=cos(2pi w y/256), c1=-sin(2pi w y/256)
// TdftW (fp16): [y2 32][w 256], y2=2y+c: c0=cos(2pi w y/256), c1=-sin(2pi w y/256) (fwd)
__global__ __launch_bounds__(256) void k_tables(float* __restrict__ twFwH, float* __restrict__ twBwH,
                                                _Float16* __restrict__ Tspec, _Float16* __restrict__ TdftW){
  int id = blockIdx.x*256 + threadIdx.x;
  if (id < 4096){
    int h = id >> 5, m = id & 31;
    int xm = (m < 16) ? m : (96 + m);
    double ang = -2.0*PI_D*(double)((xm*h) & 127)/128.0;
    twFwH[id*2]   = (float)cos(ang);
    twFwH[id*2+1] = (float)sin(ang);
  } else if (id < 8192){
    int j = id - 4096;
    int m = j >> 7, h = j & 127;
    int xm = (m < 16) ? m : (96 + m);
    double ang = 2.0*PI_D*(double)((xm*h) & 127)/128.0;
    twBwH[j*2]   = (float)cos(ang);
    twBwH[j*2+1] = (float)sin(ang);
  } else if (id < 16384){
    int j = id - 8192;
    int w = j >> 5, kk = j & 31;
    int y = kk >> 1;
    double ang = 2.0*PI_D*(double)((w*y) & 255)/256.0;
    double v = (kk & 1) ? -sin(ang) : cos(ang);
    Tspec[j] = (_Float16)v;
  } else if (id < 24576){
    int j = id - 16384;
    int y2 = j >> 8, w = j & 255;
    int y = y2 >> 1;
    double ang = -2.0*PI_D*(double)((w*y) & 255)/256.0;
    double v = (y2 & 1) ? sin(ang) : cos(ang);
    TdftW[j] = (_Float16)v;
  }
}

// ---------------- collapsed 2x2 conv kernels -> fp16, layout [rs][tap][o][i] ----------------
__global__ __launch_bounds__(256) void k_buildK(const float* __restrict__ w, _Float16* __restrict__ K4h){
  int id = blockIdx.x*256 + threadIdx.x; // 0..4095 = o*64+i
  int o = id >> 6, i = id & 63;
  float w9[9];
  #pragma unroll
  for (int k=0;k<9;++k) w9[k] = w[id*9 + k];
  #pragma unroll
  for (int r=0;r<2;++r){
    #pragma unroll
    for (int s=0;s<2;++s){
      int rs = r*2+s;
      #pragma unroll
      for (int a=0;a<2;++a){
        int klo = (r==0) ? (a==0?0:1) : (a==0?0:2);
        int khi = (r==0) ? (a==0?0:2) : (a==0?1:2);
        #pragma unroll
        for (int b=0;b<2;++b){
          int llo = (s==0) ? (b==0?0:1) : (b==0?0:2);
          int lhi = (s==0) ? (b==0?0:2) : (b==0?1:2);
          float sum = 0.f;
          for (int kh=klo; kh<=khi; ++kh)
            for (int kw=llo; kw<=lhi; ++kw)
              sum += w9[kh*3+kw];
          K4h[((size_t)((rs*4) + a*2+b)*64 + o)*64 + i] = (_Float16)sum;
        }
      }
    }
  }
}

// ---------------- updim 1x1 conv (C=2 -> E=64) ----------------
__global__ __launch_bounds__(256) void k_updim(const float* __restrict__ sv, const float* __restrict__ w,
                                               const float* __restrict__ b, float* __restrict__ u){
  size_t idx = (size_t)blockIdx.x*256 + threadIdx.x;
  int pos = (int)(idx & 32767);
  int e   = (int)((idx >> 15) & 63);
  int n   = (int)(idx >> 21);
  float v0 = sv[(size_t)n*65536 + pos];
  float v1 = sv[(size_t)n*65536 + 32768 + pos];
  u[idx] = w[e*2+0]*v0 + w[e*2+1]*v1 + b[e];
}

// ---------------- MFMA collapsed conv, all 4 parities per block ----------------
__global__ __launch_bounds__(512, 2) void k_conv_mfma(const float* __restrict__ u,
                                                      const _Float16* __restrict__ K4h,
                                                      const float* __restrict__ sb,
                                                      float* __restrict__ y00,
                                                      float* __restrict__ part){
  __shared__ _Float16 Xs[25344]; // 6*66*64
  const int tid = threadIdx.x;
  int bid = blockIdx.x;
  int qt4 = bid & 3;
  int pg  = (bid >> 2) & 31;
  int n   = bid >> 7;
  int p0 = pg*4, q0 = qt4*64;

  for (int idx = tid; idx < 18432; idx += 512){
    int c5  = idx & 31;
    int ip1 = (idx >> 5) & 1;
    int iphi= (idx >> 6) & 15;
    int t3  = idx >> 10;
    int chi = t3 % 3;
    int row = t3 / 3;
    int c = chi*32 + c5;
    if (c < 66){
      int i = iphi*4 + ip1*2;
      int grow = p0 - 1 + row;
      int gcol = q0 - 1 + c;
      float v0 = 0.f, v1 = 0.f;
      if (grow >= 0 && grow < 128 && gcol >= 0 && gcol < 256){
        const float* up = u + ((size_t)(n*64 + i)*128 + grow)*256 + gcol;
        v0 = up[0]; v1 = up[32768];
      }
      int g = i >> 3;
      int addr = ((row*66 + c) << 6) + (((c + g) & 7) << 3) + (i & 7);
      union { _Float16 h[2]; unsigned int u32; } pk;
      pk.h[0] = (_Float16)v0; pk.h[1] = (_Float16)v1;
      *(unsigned int*)(Xs + addr) = pk.u32;
    }
  }
  __syncthreads();

  int wid  = tid >> 6;
  int lane = tid & 63;
  int rs = wid & 3;
  int ot = wid >> 2;
  int r = rs >> 1, s = rs & 1;
  int l31 = lane & 31;
  int l5  = lane >> 5;

  h8 af[4][4];
  {
    const _Float16* kb = K4h + ((size_t)(rs*4)*64 + ot*32 + l31)*64 + l5*8;
    #pragma unroll
    for (int tap=0;tap<4;++tap)
      #pragma unroll
      for (int ks=0;ks<4;++ks)
        af[tap][ks] = *(const h8*)(kb + (size_t)tap*4096 + ks*16);
  }
  float bias_j[16];
  #pragma unroll
  for (int j=0;j<16;++j) bias_j[j] = sb[ot*32 + (j&3) + 8*(j>>2) + 4*l5];

  float s1[16], s2[16];
  #pragma unroll
  for (int j=0;j<16;++j){ s1[j]=0.f; s2[j]=0.f; }

  for (int dp=0; dp<4; ++dp){
    f16v acc0, acc1;
    #pragma unroll
    for (int j=0;j<16;++j){ acc0[j] = bias_j[j]; acc1[j] = bias_j[j]; }
    #pragma unroll
    for (int tap=0;tap<4;++tap){
      int a = tap >> 1, b = tap & 1;
      int row = dp + a + r;
      int rowbase = (row*66) << 6;
      {
        int c = l31 + s + b;
        int cb = rowbase + (c << 6);
        #pragma unroll
        for (int ks=0;ks<4;++ks){
          int addr = cb + (((c + ks*2 + l5) & 7) << 3);
          h8 bf = *(const h8*)(Xs + addr);
          acc0 = __builtin_amdgcn_mfma_f32_32x32x16_f16(af[tap][ks], bf, acc0, 0,0,0);
        }
      }
      {
        int c = 32 + l31 + s + b;
        int cb = rowbase + (c << 6);
        #pragma unroll
        for (int ks=0;ks<4;++ks){
          int addr = cb + (((c + ks*2 + l5) & 7) << 3);
          h8 bf = *(const h8*)(Xs + addr);
          acc1 = __builtin_amdgcn_mfma_f32_32x32x16_f16(af[tap][ks], bf, acc1, 0,0,0);
        }
      }
    }
    #pragma unroll
    for (int j=0;j<16;++j){
      float v0 = acc0[j], v1 = acc1[j];
      s1[j] += v0 + v1;
      s2[j] += v0*v0 + v1*v1;
    }
    if (rs == 0){
      int p = p0 + dp;
      #pragma unroll
      for (int j=0;j<16;++j){
        int o = ot*32 + (j&3) + 8*(j>>2) + 4*l5;
        float* yp = y00 + ((size_t)(n*64+o)*128 + p)*256 + q0 + l31;
        yp[0]  = acc0[j];
        yp[32] = acc1[j];
      }
    }
  }

  #pragma unroll
  for (int m=1;m<=16;m<<=1){
    #pragma unroll
    for (int j=0;j<16;++j){
      s1[j] += __shfl_xor(s1[j], m, 64);
      s2[j] += __shfl_xor(s2[j], m, 64);
    }
  }
  if (l31 == 0){
    float* pp = part + ((size_t)bid*4 + rs)*128;
    #pragma unroll
    for (int j=0;j<16;++j){
      int o = ot*32 + (j&3) + 8*(j>>2) + 4*l5;
      pp[o*2]   = s1[j];
      pp[o*2+1] = s2[j];
    }
  }
}

// ---------------- instance-norm statistics reduce ----------------
__global__ __launch_bounds__(256) void k_stats2(const float* __restrict__ part, float* __restrict__ stats){
  int n = blockIdx.x >> 6, o = blockIdx.x & 63;
  double a1=0.0, a2=0.0;
  #pragma unroll
  for (int it=0; it<2; ++it){
    int idx = threadIdx.x + it*256;
    int pg = idx >> 4, qt4 = (idx>>2)&3, rs = idx&3;
    int bid = (n*32 + pg)*4 + qt4;
    a1 += (double)part[((size_t)bid*4 + rs)*128 + o*2];
    a2 += (double)part[((size_t)bid*4 + rs)*128 + o*2+1];
  }
  __shared__ double r1[256], r2[256];
  r1[threadIdx.x]=a1; r2[threadIdx.x]=a2; __syncthreads();
  for (int st=128; st>0; st>>=1){
    if (threadIdx.x<st){ r1[threadIdx.x]+=r1[threadIdx.x+st]; r2[threadIdx.x]+=r2[threadIdx.x+st]; }
    __syncthreads();
  }
  if (threadIdx.x==0){
    double mu  = r1[0] / 131072.0;
    double var = r2[0] / 131072.0 - mu*mu;
    stats[blockIdx.x*2]   = (float)mu;
    stats[blockIdx.x*2+1] = (float)(1.0/sqrt(var + 1e-5));
  }
}

// ---------------- norm + gelu + fp32 -> fp16 ----------------
__global__ __launch_bounds__(256) void k_normgelu(const float* __restrict__ x, const float* __restrict__ stats,
                                                  _Float16* __restrict__ out){
  size_t idx = ((size_t)blockIdx.x*256 + threadIdx.x)*4;
  int no = (int)(idx >> 15);
  float mu = stats[no*2], istd = stats[no*2+1];
  float4 v = *(const float4*)(x + idx);
  h4v o;
  o[0] = (_Float16)gelu_f((v.x-mu)*istd);
  o[1] = (_Float16)gelu_f((v.y-mu)*istd);
  o[2] = (_Float16)gelu_f((v.z-mu)*istd);
  o[3] = (_Float16)gelu_f((v.w-mu)*istd);
  *(h4v*)(out + idx) = o;
}

// ---------------- forward DFT along W via MFMA ----------------
// grid 640: (n, h-pair). M=128 rows (2h x 64e), N=32 (y2), K=256 (w).
__global__ __launch_bounds__(256, 2) void k_dftW_mfma(const _Float16* __restrict__ act,
                                                      const _Float16* __restrict__ TdftW,
                                                      float* __restrict__ Cy){
  __shared__ _Float16 Ax[32768]; // [a 128][256] chunk-swizzled
  __shared__ _Float16 Bt[8192];  // [y2 32][256] chunk-swizzled
  int tid = threadIdx.x;
  int hp = blockIdx.x & 63, n = blockIdx.x >> 6;
  int h0 = hp*2;

  {
    int a = tid >> 1;           // 0..127
    int ws = (tid & 1) * 128;
    int e = a & 63, ht = a >> 6;
    const _Float16* src = act + ((size_t)(n*64+e))*32768 + (size_t)(h0+ht)*256 + ws;
    #pragma unroll
    for (int k=0;k<16;++k){
      h8 v = *(const h8*)(src + k*8);
      int wq = (ws >> 3) + k;         // chunk index 0..31
      int chunk = wq ^ (a & 7);
      *(h8*)(Ax + a*256 + chunk*8) = v;
    }
  }
  {
    int y2 = tid & 31, ws = (tid >> 5) * 32;
    const _Float16* src = TdftW + y2*256 + ws;
    #pragma unroll
    for (int k=0;k<4;++k){
      h8 v = *(const h8*)(src + k*8);
      int wq = (ws >> 3) + k;
      int chunk = wq ^ (y2 & 7);
      *(h8*)(Bt + y2*256 + chunk*8) = v;
    }
  }
  __syncthreads();

  int lane = tid & 63;
  int l31 = lane & 31, l5 = lane >> 5;
  int mt = tid >> 6;
  int a = mt*32 + l31;

  f16v acc;
  #pragma unroll
  for (int j=0;j<16;++j) acc[j] = 0.f;
  #pragma unroll
  for (int ks=0;ks<16;++ks){
    int kb = ks*16 + l5*8;
    int cA = (kb>>3) ^ (a & 7);
    int cB = (kb>>3) ^ (l31 & 7);
    h8 af = *(const h8*)(Ax + a*256 + cA*8);
    h8 bf = *(const h8*)(Bt + l31*256 + cB*8);
    acc = __builtin_amdgcn_mfma_f32_32x32x16_f16(af, bf, acc, 0,0,0);
  }
  #pragma unroll
  for (int j=0;j<16;++j){
    int arow = mt*32 + (j&3) + 8*(j>>2) + 4*l5;
    int ht = arow >> 6, e = arow & 63;
    Cy[((size_t)(n*64+e)*128 + h0+ht)*32 + l31] = acc[j];
  }
}

// ---------------- forward DFT along H (32 modes) ----------------
__global__ __launch_bounds__(256) void k_dftH(const float* __restrict__ Cy, const float* __restrict__ twg,
                                              float* __restrict__ coeff){
  __shared__ float CS[128*32];
  __shared__ float TW[128*64];
  int tid = threadIdx.x;
  size_t base = (size_t)blockIdx.x * 4096;
  for (int t=tid; t<4096; t+=256) CS[t] = Cy[base + t];
  for (int t=tid; t<8192; t+=256) TW[t] = twg[t];
  __syncthreads();
  int m = tid >> 3, yg = tid & 7;
  float c0r=0.f,c0i=0.f,c1r=0.f,c1i=0.f;
  for (int h=0; h<128; ++h){
    float2 tw = *(const float2*)(TW + h*64 + m*2);
    float2 v0 = *(const float2*)(CS + h*32 + yg*4);
    float2 v1 = *(const float2*)(CS + h*32 + yg*4 + 2);
    c0r += v0.x*tw.x - v0.y*tw.y;
    c0i += v0.x*tw.y + v0.y*tw.x;
    c1r += v1.x*tw.x - v1.y*tw.y;
    c1i += v1.x*tw.y + v1.y*tw.x;
  }
  size_t ob = (size_t)blockIdx.x*1024 + m*32 + yg*4;
  *(float2*)(coeff+ob)   = make_float2(c0r,c0i);
  *(float2*)(coeff+ob+2) = make_float2(c1r,c1i);
}

// ---------------- spectral mode mixing ----------------
__global__ __launch_bounds__(256) void k_modemix(const float* __restrict__ coeff,
                                                 const float* __restrict__ wr, const float* __restrict__ wi,
                                                 float* __restrict__ mo){
  __shared__ float CS[5*64*32];
  int bid = blockIdx.x;
  int ng = bid & 1;
  int oq = (bid >> 1) & 3;
  int m  = bid >> 3;
  int blk = m >> 4, mm = m & 15;
  int n0 = ng*5;
  int tid = threadIdx.x;
  for (int t=tid; t<2560; t+=256){
    int ni = t >> 3, prt = t & 7;
    int nn = ni >> 6, i = ni & 63;
    *(float4*)(CS + (nn*64+i)*32 + prt*4) =
      *(const float4*)(coeff + ((size_t)((n0+nn)*64+i)*32 + m)*32 + prt*4);
  }
  __syncthreads();
  int ty = tid >> 4, y = tid & 15;
  int o = oq*16 + ty;
  float ar[5], ai[5];
  #pragma unroll
  for (int nn=0;nn<5;++nn){ ar[nn]=0.f; ai[nn]=0.f; }
  const float* wrb = wr + ((size_t)(blk*64)*64 + o)*256 + mm*16 + y;
  const float* wib = wi + ((size_t)(blk*64)*64 + o)*256 + mm*16 + y;
  for (int i=0;i<64;++i){
    float wrv = wrb[(size_t)i*16384];
    float wiv = wib[(size_t)i*16384];
    const float* cp = CS + i*32 + y*2;
    #pragma unroll
    for (int nn=0;nn<5;++nn){
      float2 c2 = *(const float2*)(cp + nn*2048);
      ar[nn] += c2.x*wrv - c2.y*wiv;
      ai[nn] += c2.x*wiv + c2.y*wrv;
    }
  }
  #pragma unroll
  for (int nn=0;nn<5;++nn)
    *(float2*)(mo + (((size_t)((n0+nn)*64+o)*32 + m)*16 + y)*2) = make_float2(ar[nn], ai[nn]);
}

// ---------------- inverse DFT along H ----------------
__global__ __launch_bounds__(256) void k_idftH(const float* __restrict__ mo, const float* __restrict__ twg,
                                               float* __restrict__ G){
  __shared__ float MS[1024];
  __shared__ float TW[8192];
  int tid = threadIdx.x;
  size_t base = (size_t)blockIdx.x * 1024;
  for (int t=tid; t<1024; t+=256) MS[t] = mo[base + t];
  for (int t=tid; t<8192; t+=256) TW[t] = twg[t];
  __syncthreads();
  int y = tid & 15, hg = tid >> 4;
  float gr[8], gi[8];
  #pragma unroll
  for (int k=0;k<8;++k){ gr[k]=0.f; gi[k]=0.f; }
  for (int mI=0;mI<32;++mI){
    float2 c = *(const float2*)(MS + mI*32 + y*2);
    const float* twp = TW + mI*256 + hg*16;
    #pragma unroll
    for (int k=0;k<8;++k){
      float2 tw = *(const float2*)(twp + k*2);
      gr[k] += c.x*tw.x - c.y*tw.y;
      gi[k] += c.x*tw.y + c.y*tw.x;
    }
  }
  float f = (y==0) ? (1.f/32768.f) : (2.f/32768.f);
  #pragma unroll
  for (int k=0;k<8;++k){
    int h = hg*8+k;
    *(float2*)(G + ((size_t)blockIdx.x*128 + h)*32 + y*2) = make_float2(gr[k]*f, gi[k]*f);
  }
}

// ---------------- fused skip-GEMM + inverse DFT-W + gelu via MFMA ----------------
// grid 1280: (n, h). C[o 64][w 256] = [cw | G] (64x96) x [X ; Tspec] (96x256)
__global__ __launch_bounds__(256, 2) void k_combine_mfma(const _Float16* __restrict__ act_in,
                                                         const float* __restrict__ G,
                                                         const _Float16* __restrict__ Tspec,
                                                         const float* __restrict__ cw,
                                                         const float* __restrict__ cb,
                                                         _Float16* __restrict__ act_out){
  __shared__ _Float16 Bx[32768]; // [w 256][k 128] chunk-swizzled
  __shared__ _Float16 At[8192];  // [o 64][k 128] chunk-swizzled
  int tid = threadIdx.x;
  int h = blockIdx.x & 127, n = blockIdx.x >> 7;

  // ---- stage X: transpose [i][w] -> Bx[w][k=i], k-chunks 0..7 ----
  {
    int p = tid >> 3;          // i-pair 0..31
    int wl = tid & 7;
    int i0 = 2*p;
    const _Float16* r0 = act_in + (size_t)(n*64+i0)*32768 + (size_t)h*256;
    const _Float16* r1 = r0 + 32768;
    int cbase = (p >> 2);      // = i0>>3
    #pragma unroll
    for (int jj=0; jj<32; ++jj){
      int w = wl + 8*jj;
      union { _Float16 hh[2]; unsigned u; } pk;
      pk.hh[0] = r0[w]; pk.hh[1] = r1[w];
      int chunk = cbase ^ (w & 7);
      *(unsigned*)(Bx + w*128 + chunk*8 + (i0 & 7)) = pk.u;
    }
  }
  // ---- stage A: cw (k 0..63) ----
  {
    int o = tid >> 2, seg = (tid & 3)*16;
    float4 c0 = *(const float4*)(cw + o*64 + seg);
    float4 c1 = *(const float4*)(cw + o*64 + seg + 4);
    float4 c2 = *(const float4*)(cw + o*64 + seg + 8);
    float4 c3 = *(const float4*)(cw + o*64 + seg + 12);
    h8 v0, v1;
    v0[0]=(_Float16)c0.x; v0[1]=(_Float16)c0.y; v0[2]=(_Float16)c0.z; v0[3]=(_Float16)c0.w;
    v0[4]=(_Float16)c1.x; v0[5]=(_Float16)c1.y; v0[6]=(_Float16)c1.z; v0[7]=(_Float16)c1.w;
    v1[0]=(_Float16)c2.x; v1[1]=(_Float16)c2.y; v1[2]=(_Float16)c2.z; v1[3]=(_Float16)c2.w;
    v1[4]=(_Float16)c3.x; v1[5]=(_Float16)c3.y; v1[6]=(_Float16)c3.z; v1[7]=(_Float16)c3.w;
    int cb0 = (seg>>3) ^ (o & 7);
    int cb1 = ((seg>>3)+1) ^ (o & 7);
    *(h8*)(At + o*128 + cb0*8) = v0;
    *(h8*)(At + o*128 + cb1*8) = v1;
  }
  // ---- stage A: G (k 64..95) ----
  {
    int o = tid >> 2, gq = tid & 3;
    const float* gp = G + ((size_t)(n*64+o)*128 + h)*32 + gq*8;
    float4 g0 = *(const float4*)(gp);
    float4 g1 = *(const float4*)(gp + 4);
    h8 v;
    v[0]=(_Float16)g0.x; v[1]=(_Float16)g0.y; v[2]=(_Float16)g0.z; v[3]=(_Float16)g0.w;
    v[4]=(_Float16)g1.x; v[5]=(_Float16)g1.y; v[6]=(_Float16)g1.z; v[7]=(_Float16)g1.w;
    int chunk = (8 + gq) ^ (o & 7);
    *(h8*)(At + o*128 + chunk*8) = v;
  }
  // ---- stage B: Tspec rows (k 64..95) ----
  {
    int w = tid;
    const _Float16* tp = Tspec + w*32;
    #pragma unroll
    for (int cc=0; cc<4; ++cc){
      h8 v = *(const h8*)(tp + cc*8);
      int chunk = (8 + cc) ^ (w & 7);
      *(h8*)(Bx + w*128 + chunk*8) = v;
    }
  }
  __syncthreads();

  int lane = tid & 63;
  int l31 = lane & 31, l5 = lane >> 5;
  int w0 = tid >> 6;
  int mt = w0 & 1, ng = w0 >> 1;
  int o_lane = mt*32 + l31;

  h8 af[6];
  #pragma unroll
  for (int ks=0;ks<6;++ks){
    int kb = ks*16 + l5*8;
    int chunk = (kb>>3) ^ (o_lane & 7);
    af[ks] = *(const h8*)(At + o_lane*128 + chunk*8);
  }
  float bias[16];
  #pragma unroll
  for (int j=0;j<16;++j) bias[j] = cb[mt*32 + (j&3) + 8*(j>>2) + 4*l5];

  f16v acc[4];
  #pragma unroll
  for (int q=0;q<4;++q)
    #pragma unroll
    for (int j=0;j<16;++j) acc[q][j] = bias[j];

  #pragma unroll
  for (int q=0;q<4;++q){
    int w = (ng*4+q)*32 + l31;
    const _Float16* bbase = Bx + w*128;
    int w7 = w & 7;
    #pragma unroll
    for (int ks=0;ks<6;++ks){
      int kb = ks*16 + l5*8;
      int chunk = (kb>>3) ^ w7;
      h8 bf = *(const h8*)(bbase + chunk*8);
      acc[q] = __builtin_amdgcn_mfma_f32_32x32x16_f16(af[ks], bf, acc[q], 0,0,0);
    }
  }

  #pragma unroll
  for (int q=0;q<4;++q){
    int wcol = (ng*4+q)*32 + l31;
    #pragma unroll
    for (int j=0;j<16;++j){
      int o = mt*32 + (j&3) + 8*(j>>2) + 4*l5;
      float v = gelu_f(acc[q][j]);
      act_out[(size_t)(n*64+o)*32768 + (size_t)h*256 + wcol] = (_Float16)v;
    }
  }
}

// ---------------- downdim 1x1 conv (E=64 -> C=2), fp16 in ----------------
__global__ __launch_bounds__(256) void k_downdim(const _Float16* __restrict__ x, const float* __restrict__ wd,
                                                 const float* __restrict__ bd, float* __restrict__ out){
  size_t idx = (size_t)blockIdx.x*256 + threadIdx.x;
  int n = (int)(idx >> 15);
  int pos = (int)(idx & 32767);
  float a0 = bd[0], a1 = bd[1];
  const _Float16* xp = x + (size_t)n*2097152 + pos;
  for (int e=0;e<64;++e){
    float v = (float)xp[(size_t)e*32768];
    a0 += wd[e]*v;
    a1 += wd[64+e]*v;
  }
  out[(size_t)n*65536 + pos] = a0;
  out[(size_t)n*65536 + 32768 + pos] = a1;
}

extern "C" void kernel_launch(void* const* d_in, const int* in_sizes, int n_in,
                              void* d_out, int out_size, void* d_ws, size_t ws_size,
                              hipStream_t stream) {
  const float* sv  = (const float*)d_in[0];
  const float* upw = (const float*)d_in[1];
  const float* upb = (const float*)d_in[2];
  const float* smw = (const float*)d_in[3];
  const float* smb = (const float*)d_in[4];
  const float* fwr = (const float*)d_in[5];
  const float* fwi = (const float*)d_in[6];
  const float* fcw = (const float*)d_in[7];
  const float* fcb = (const float*)d_in[8];
  const float* ddw = (const float*)d_in[9];
  const float* ddb = (const float*)d_in[10];
  float* out = (float*)d_out;

  float* W = (float*)d_ws;
  float* y00  = W;                          // 20971520 floats (conv out)
  float* bufU = W + 20971520;               // 20971520 floats (updim out; dead after conv)
  _Float16* actA = (_Float16*)(W + 20971520);   // 20971520 halves (overlays bufU after conv)
  _Float16* actB = (_Float16*)(W + 31457280);   // 20971520 halves
  float* small = W + 41943040;              // scratch region
  float* Cy    = small;                     // 2621440
  float* G     = small + 2621440;           // 2621440
  float* coeff = small + 5242880;           // 655360
  float* mo    = small + 5898240;           // 655360
  float* part  = small;                     // aliases Cy (conv phase only)
  float* stats = W + 48496640;              // 1280
  _Float16* K4h = (_Float16*)(stats + 1280);    // 65536 halves (in 65536-float region)
  float* twFwH = stats + 1280 + 65536;      // 8192
  float* twBwH = twFwH + 8192;              // 8192
  _Float16* Tspec = (_Float16*)(twBwH + 8192);      // 8192 halves (4096 floats)
  _Float16* TdftW = (_Float16*)(twBwH + 8192 + 4096); // 8192 halves

  k_tables<<<96,256,0,stream>>>(twFwH, twBwH, Tspec, TdftW);
  k_buildK<<<16,256,0,stream>>>(smw, K4h);
  k_updim<<<81920,256,0,stream>>>(sv, upw, upb, bufU);
  k_conv_mfma<<<1280,512,0,stream>>>(bufU, K4h, smb, y00, part);
  k_stats2<<<640,256,0,stream>>>(part, stats);
  k_normgelu<<<20480,256,0,stream>>>(y00, stats, actA);

  _Float16* xa = actA; _Float16* xb = actB;
  for (int l=0;l<4;++l){
    k_dftW_mfma<<<640,256,0,stream>>>(xa, TdftW, Cy);
    k_dftH<<<640,256,0,stream>>>(Cy, twFwH, coeff);
    k_modemix<<<256,256,0,stream>>>(coeff, fwr + (size_t)l*2097152, fwi + (size_t)l*2097152, mo);
    k_idftH<<<640,256,0,stream>>>(mo, twBwH, G);
    k_combine_mfma<<<1280,256,0,stream>>>(xa, G, Tspec, fcw + (size_t)l*4096, fcb + (size_t)l*64, xb);
    _Float16* t = xa; xa = xb; xb = t;
  }
  k_downdim<<<1280,256,0,stream>>>(xa, ddw, ddb, out);
}

// Round 4
// 628.395 us; speedup vs baseline: 3.3647x; 1.1154x over previous
//
#include <hip/hip_runtime.h>
#include <math.h>

#define PI_D 3.14159265358979323846

// N=10 images, E=64 ch, H=128, W=256, M=16 modes, L=4 layers

typedef _Float16 h8 __attribute__((ext_vector_type(8)));
typedef float f16v __attribute__((ext_vector_type(16)));

__device__ __forceinline__ float gelu_f(float v){
  return 0.5f*v*(1.0f + erff(v*0.70710678118654752440f));
}

// ---------------- tables ----------------
__global__ __launch_bounds__(256) void k_tables(float* __restrict__ twFwH, float* __restrict__ twBwH,
                                                _Float16* __restrict__ Tspec, _Float16* __restrict__ TdftW){
  int id = blockIdx.x*256 + threadIdx.x;
  if (id < 4096){
    int h = id >> 5, m = id & 31;
    int xm = (m < 16) ? m : (96 + m);
    double ang = -2.0*PI_D*(double)((xm*h) & 127)/128.0;
    twFwH[id*2]   = (float)cos(ang);
    twFwH[id*2+1] = (float)sin(ang);
  } else if (id < 8192){
    int j = id - 4096;
    int m = j >> 7, h = j & 127;
    int xm = (m < 16) ? m : (96 + m);
    double ang = 2.0*PI_D*(double)((xm*h) & 127)/128.0;
    twBwH[j*2]   = (float)cos(ang);
    twBwH[j*2+1] = (float)sin(ang);
  } else if (id < 16384){
    int j = id - 8192;
    int w = j >> 5, kk = j & 31;
    int y = kk >> 1;
    double ang = 2.0*PI_D*(double)((w*y) & 255)/256.0;
    double v = (kk & 1) ? -sin(ang) : cos(ang);
    Tspec[j] = (_Float16)v;
  } else if (id < 24576){
    int j = id - 16384;
    int y2 = j >> 8, w = j & 255;
    int y = y2 >> 1;
    double ang = -2.0*PI_D*(double)((w*y) & 255)/256.0;
    double v = (y2 & 1) ? sin(ang) : cos(ang);
    TdftW[j] = (_Float16)v;
  }
}

// ---------------- fold updim into collapsed conv: Keff[o][rs*4+tap][4] = {c0,c1,kb,0} ----------------
__global__ __launch_bounds__(256) void k_foldK(const float* __restrict__ smw, const float* __restrict__ upw,
                                               const float* __restrict__ upb, float* __restrict__ Keff){
  int id = blockIdx.x*256 + threadIdx.x; // 0..1023 = o*16 + rs*4 + tap
  if (id >= 1024) return;
  int o = id >> 4, rs = (id >> 2) & 3, tap = id & 3;
  int r = rs >> 1, s = rs & 1, a = tap >> 1, b = tap & 1;
  int klo = (r==0) ? (a==0?0:1) : (a==0?0:2);
  int khi = (r==0) ? (a==0?0:2) : (a==0?1:2);
  int llo = (s==0) ? (b==0?0:1) : (b==0?0:2);
  int lhi = (s==0) ? (b==0?0:2) : (b==0?1:2);
  float a0=0.f, a1=0.f, ab=0.f;
  for (int i=0;i<64;++i){
    float t = 0.f;
    for (int kh=klo; kh<=khi; ++kh)
      for (int kw=llo; kw<=lhi; ++kw)
        t += smw[((size_t)o*64+i)*9 + kh*3+kw];
    a0 += t*upw[i*2];
    a1 += t*upw[i*2+1];
    ab += t*upb[i];
  }
  *(float4*)(Keff + o*64 + (rs*4+tap)*4) = make_float4(a0, a1, ab, 0.f);
}

// ---------------- fused updim+conv statistics over all 4 parities ----------------
// grid 1280 = n*128+p; 256 threads = q; no y stores, only per-(block,wave) partial stats
__global__ __launch_bounds__(256) void k_statconv(const float* __restrict__ sv,
                                                  const float* __restrict__ Keff,
                                                  float* __restrict__ part){
  __shared__ float SV[6*260]; // [dr 3][ch 2][260]
  int bid = blockIdx.x;
  int p = bid & 127, n = bid >> 7;
  int tid = threadIdx.x;
  for (int t = tid; t < 1548; t += 256){
    int dr = t / 516;
    int rem = t - dr*516;
    int ch = rem / 258;
    int ci = rem - ch*258;
    int row = p - 1 + dr;
    int col = ci - 1;
    float v = 0.f;
    if (row >= 0 && row < 128 && col >= 0 && col < 256)
      v = sv[((size_t)(n*2+ch)*128 + row)*256 + col];
    SV[(dr*2+ch)*260 + ci] = v;
  }
  __syncthreads();

  int q = tid;
  int lane = tid & 63, wid = tid >> 6;
  float x0[9], x1[9], ib[9];
  #pragma unroll
  for (int dr=0; dr<3; ++dr)
    #pragma unroll
    for (int dc=0; dc<3; ++dc){
      x0[dr*3+dc] = SV[(dr*2+0)*260 + q + dc];
      x1[dr*3+dc] = SV[(dr*2+1)*260 + q + dc];
    }
  float rowok[3]; rowok[0] = (p>0)?1.f:0.f; rowok[1]=1.f; rowok[2] = (p<127)?1.f:0.f;
  float colok[3]; colok[0] = (q>0)?1.f:0.f; colok[1]=1.f; colok[2] = (q<255)?1.f:0.f;
  #pragma unroll
  for (int dr=0;dr<3;++dr)
    #pragma unroll
    for (int dc=0;dc<3;++dc) ib[dr*3+dc] = rowok[dr]*colok[dc];

  float S1 = 0.f, S2 = 0.f;
  for (int o=0; o<64; ++o){
    const float4* kp = (const float4*)(Keff + o*64);   // uniform -> s_load
    float s1 = 0.f, s2 = 0.f;
    #pragma unroll
    for (int r=0;r<2;++r){
      #pragma unroll
      for (int s=0;s<2;++s){
        float y = 0.f;
        #pragma unroll
        for (int a=0;a<2;++a){
          #pragma unroll
          for (int b=0;b<2;++b){
            float4 kv = kp[((r*2+s)*2+a)*2 + b];
            int d = (r+a)*3 + (s+b);
            y += kv.x*x0[d] + kv.y*x1[d] + kv.z*ib[d];
          }
        }
        s1 += y; s2 += y*y;
      }
    }
    #pragma unroll
    for (int m=1; m<64; m<<=1){
      s1 += __shfl_xor(s1, m, 64);
      s2 += __shfl_xor(s2, m, 64);
    }
    if (o == lane){ S1 = s1; S2 = s2; }
  }
  part[((size_t)bid*4 + wid)*128 + lane*2]   = S1;
  part[((size_t)bid*4 + wid)*128 + lane*2+1] = S2;
}

// ---------------- instance-norm statistics reduce ----------------
__global__ __launch_bounds__(256) void k_stats2(const float* __restrict__ part, float* __restrict__ stats){
  int n = blockIdx.x >> 6, o = blockIdx.x & 63;
  double a1=0.0, a2=0.0;
  #pragma unroll
  for (int it=0; it<2; ++it){
    int idx = threadIdx.x + it*256;   // p*4 + w
    int bid = n*128 + (idx >> 2);
    int w = idx & 3;
    a1 += (double)part[((size_t)bid*4 + w)*128 + o*2];
    a2 += (double)part[((size_t)bid*4 + w)*128 + o*2+1];
  }
  __shared__ double r1[256], r2[256];
  r1[threadIdx.x]=a1; r2[threadIdx.x]=a2; __syncthreads();
  for (int st=128; st>0; st>>=1){
    if (threadIdx.x<st){ r1[threadIdx.x]+=r1[threadIdx.x+st]; r2[threadIdx.x]+=r2[threadIdx.x+st]; }
    __syncthreads();
  }
  if (threadIdx.x==0){
    double mu  = r1[0] / 131072.0;
    double var = r2[0] / 131072.0 - mu*mu;
    stats[blockIdx.x*2]   = (float)mu;
    stats[blockIdx.x*2+1] = (float)(1.0/sqrt(var + 1e-5));
  }
}

// ---------------- fused updim+conv (parity 0 only) + norm + gelu -> fp16 ----------------
// grid 1280 = n*128+p; 256 threads = q
__global__ __launch_bounds__(256) void k_convnorm(const float* __restrict__ sv,
                                                  const float* __restrict__ Keff,
                                                  const float* __restrict__ stats,
                                                  _Float16* __restrict__ act){
  __shared__ float SV[4*260]; // rows p-1,p x ch 2 x 260
  int bid = blockIdx.x;
  int p = bid & 127, n = bid >> 7;
  int tid = threadIdx.x;
  for (int t = tid; t < 1032; t += 256){
    int dr = t / 516;
    int rem = t - dr*516;
    int ch = rem / 258;
    int ci = rem - ch*258;
    int row = p - 1 + dr;
    int col = ci - 1;
    float v = 0.f;
    if (row >= 0 && col >= 0 && col < 256)
      v = sv[((size_t)(n*2+ch)*128 + row)*256 + col];
    SV[(dr*2+ch)*260 + ci] = v;
  }
  __syncthreads();

  int q = tid;
  float x0[4], x1[4], ib[4];
  float rowok0 = (p>0)?1.f:0.f;
  float colok0 = (q>0)?1.f:0.f;
  #pragma unroll
  for (int a=0;a<2;++a)
    #pragma unroll
    for (int b=0;b<2;++b){
      x0[a*2+b] = SV[(a*2+0)*260 + q + b];
      x1[a*2+b] = SV[(a*2+1)*260 + q + b];
      ib[a*2+b] = (a==0?rowok0:1.f) * (b==0?colok0:1.f);
    }

  for (int o=0; o<64; ++o){
    const float4* kp = (const float4*)(Keff + o*64);   // rs=0 slice at [0..3]
    float y = 0.f;
    #pragma unroll
    for (int t=0;t<4;++t){
      float4 kv = kp[t];
      y += kv.x*x0[t] + kv.y*x1[t] + kv.z*ib[t];
    }
    float mu = stats[(n*64+o)*2], istd = stats[(n*64+o)*2+1];
    float v = (y - mu)*istd;
    act[((size_t)(n*64+o)*128 + p)*256 + q] = (_Float16)gelu_f(v);
  }
}

// ---------------- forward DFT along W via MFMA ----------------
__global__ __launch_bounds__(256, 2) void k_dftW_mfma(const _Float16* __restrict__ act,
                                                      const _Float16* __restrict__ TdftW,
                                                      float* __restrict__ Cy){
  __shared__ _Float16 Ax[32768]; // [a 128][256] chunk-swizzled
  __shared__ _Float16 Bt[8192];  // [y2 32][256] chunk-swizzled
  int tid = threadIdx.x;
  int hp = blockIdx.x & 63, n = blockIdx.x >> 6;
  int h0 = hp*2;

  {
    int a = tid >> 1;
    int ws = (tid & 1) * 128;
    int e = a & 63, ht = a >> 6;
    const _Float16* src = act + ((size_t)(n*64+e))*32768 + (size_t)(h0+ht)*256 + ws;
    #pragma unroll
    for (int k=0;k<16;++k){
      h8 v = *(const h8*)(src + k*8);
      int wq = (ws >> 3) + k;
      int chunk = wq ^ (a & 7);
      *(h8*)(Ax + a*256 + chunk*8) = v;
    }
  }
  {
    int y2 = tid & 31, ws = (tid >> 5) * 32;
    const _Float16* src = TdftW + y2*256 + ws;
    #pragma unroll
    for (int k=0;k<4;++k){
      h8 v = *(const h8*)(src + k*8);
      int wq = (ws >> 3) + k;
      int chunk = wq ^ (y2 & 7);
      *(h8*)(Bt + y2*256 + chunk*8) = v;
    }
  }
  __syncthreads();

  int lane = tid & 63;
  int l31 = lane & 31, l5 = lane >> 5;
  int mt = tid >> 6;
  int a = mt*32 + l31;

  f16v acc;
  #pragma unroll
  for (int j=0;j<16;++j) acc[j] = 0.f;
  #pragma unroll
  for (int ks=0;ks<16;++ks){
    int kb = ks*16 + l5*8;
    int cA = (kb>>3) ^ (a & 7);
    int cB = (kb>>3) ^ (l31 & 7);
    h8 af = *(const h8*)(Ax + a*256 + cA*8);
    h8 bf = *(const h8*)(Bt + l31*256 + cB*8);
    acc = __builtin_amdgcn_mfma_f32_32x32x16_f16(af, bf, acc, 0,0,0);
  }
  #pragma unroll
  for (int j=0;j<16;++j){
    int arow = mt*32 + (j&3) + 8*(j>>2) + 4*l5;
    int ht = arow >> 6, e = arow & 63;
    Cy[((size_t)(n*64+e)*128 + h0+ht)*32 + l31] = acc[j];
  }
}

// ---------------- forward DFT along H (32 modes) ----------------
__global__ __launch_bounds__(256) void k_dftH(const float* __restrict__ Cy, const float* __restrict__ twg,
                                              float* __restrict__ coeff){
  __shared__ float CS[128*32];
  __shared__ float TW[128*64];
  int tid = threadIdx.x;
  size_t base = (size_t)blockIdx.x * 4096;
  for (int t=tid; t<4096; t+=256) CS[t] = Cy[base + t];
  for (int t=tid; t<8192; t+=256) TW[t] = twg[t];
  __syncthreads();
  int m = tid >> 3, yg = tid & 7;
  float c0r=0.f,c0i=0.f,c1r=0.f,c1i=0.f;
  for (int h=0; h<128; ++h){
    float2 tw = *(const float2*)(TW + h*64 + m*2);
    float2 v0 = *(const float2*)(CS + h*32 + yg*4);
    float2 v1 = *(const float2*)(CS + h*32 + yg*4 + 2);
    c0r += v0.x*tw.x - v0.y*tw.y;
    c0i += v0.x*tw.y + v0.y*tw.x;
    c1r += v1.x*tw.x - v1.y*tw.y;
    c1i += v1.x*tw.y + v1.y*tw.x;
  }
  size_t ob = (size_t)blockIdx.x*1024 + m*32 + yg*4;
  *(float2*)(coeff+ob)   = make_float2(c0r,c0i);
  *(float2*)(coeff+ob+2) = make_float2(c1r,c1i);
}

// ---------------- spectral mode mixing ----------------
__global__ __launch_bounds__(256) void k_modemix(const float* __restrict__ coeff,
                                                 const float* __restrict__ wr, const float* __restrict__ wi,
                                                 float* __restrict__ mo){
  __shared__ float CS[5*64*32];
  int bid = blockIdx.x;
  int ng = bid & 1;
  int oq = (bid >> 1) & 3;
  int m  = bid >> 3;
  int blk = m >> 4, mm = m & 15;
  int n0 = ng*5;
  int tid = threadIdx.x;
  for (int t=tid; t<2560; t+=256){
    int ni = t >> 3, prt = t & 7;
    int nn = ni >> 6, i = ni & 63;
    *(float4*)(CS + (nn*64+i)*32 + prt*4) =
      *(const float4*)(coeff + ((size_t)((n0+nn)*64+i)*32 + m)*32 + prt*4);
  }
  __syncthreads();
  int ty = tid >> 4, y = tid & 15;
  int o = oq*16 + ty;
  float ar[5], ai[5];
  #pragma unroll
  for (int nn=0;nn<5;++nn){ ar[nn]=0.f; ai[nn]=0.f; }
  const float* wrb = wr + ((size_t)(blk*64)*64 + o)*256 + mm*16 + y;
  const float* wib = wi + ((size_t)(blk*64)*64 + o)*256 + mm*16 + y;
  for (int i=0;i<64;++i){
    float wrv = wrb[(size_t)i*16384];
    float wiv = wib[(size_t)i*16384];
    const float* cp = CS + i*32 + y*2;
    #pragma unroll
    for (int nn=0;nn<5;++nn){
      float2 c2 = *(const float2*)(cp + nn*2048);
      ar[nn] += c2.x*wrv - c2.y*wiv;
      ai[nn] += c2.x*wiv + c2.y*wrv;
    }
  }
  #pragma unroll
  for (int nn=0;nn<5;++nn)
    *(float2*)(mo + (((size_t)((n0+nn)*64+o)*32 + m)*16 + y)*2) = make_float2(ar[nn], ai[nn]);
}

// ---------------- inverse DFT along H ----------------
__global__ __launch_bounds__(256) void k_idftH(const float* __restrict__ mo, const float* __restrict__ twg,
                                               float* __restrict__ G){
  __shared__ float MS[1024];
  __shared__ float TW[8192];
  int tid = threadIdx.x;
  size_t base = (size_t)blockIdx.x * 1024;
  for (int t=tid; t<1024; t+=256) MS[t] = mo[base + t];
  for (int t=tid; t<8192; t+=256) TW[t] = twg[t];
  __syncthreads();
  int y = tid & 15, hg = tid >> 4;
  float gr[8], gi[8];
  #pragma unroll
  for (int k=0;k<8;++k){ gr[k]=0.f; gi[k]=0.f; }
  for (int mI=0;mI<32;++mI){
    float2 c = *(const float2*)(MS + mI*32 + y*2);
    const float* twp = TW + mI*256 + hg*16;
    #pragma unroll
    for (int k=0;k<8;++k){
      float2 tw = *(const float2*)(twp + k*2);
      gr[k] += c.x*tw.x - c.y*tw.y;
      gi[k] += c.x*tw.y + c.y*tw.x;
    }
  }
  float f = (y==0) ? (1.f/32768.f) : (2.f/32768.f);
  #pragma unroll
  for (int k=0;k<8;++k){
    int h = hg*8+k;
    *(float2*)(G + ((size_t)blockIdx.x*128 + h)*32 + y*2) = make_float2(gr[k]*f, gi[k]*f);
  }
}

// ---------------- fused skip-GEMM + inverse DFT-W + gelu via MFMA ----------------
__global__ __launch_bounds__(256, 2) void k_combine_mfma(const _Float16* __restrict__ act_in,
                                                         const float* __restrict__ G,
                                                         const _Float16* __restrict__ Tspec,
                                                         const float* __restrict__ cw,
                                                         const float* __restrict__ cb,
                                                         _Float16* __restrict__ act_out){
  __shared__ _Float16 Bx[32768]; // [w 256][k 128] chunk-swizzled
  __shared__ _Float16 At[8192];  // [o 64][k 128] chunk-swizzled
  int tid = threadIdx.x;
  int h = blockIdx.x & 127, n = blockIdx.x >> 7;

  {
    int p = tid >> 3;
    int wl = tid & 7;
    int i0 = 2*p;
    const _Float16* r0 = act_in + (size_t)(n*64+i0)*32768 + (size_t)h*256;
    const _Float16* r1 = r0 + 32768;
    int cbase = (p >> 2);
    #pragma unroll
    for (int jj=0; jj<32; ++jj){
      int w = wl + 8*jj;
      union { _Float16 hh[2]; unsigned u; } pk;
      pk.hh[0] = r0[w]; pk.hh[1] = r1[w];
      int chunk = cbase ^ (w & 7);
      *(unsigned*)(Bx + w*128 + chunk*8 + (i0 & 7)) = pk.u;
    }
  }
  {
    int o = tid >> 2, seg = (tid & 3)*16;
    float4 c0 = *(const float4*)(cw + o*64 + seg);
    float4 c1 = *(const float4*)(cw + o*64 + seg + 4);
    float4 c2 = *(const float4*)(cw + o*64 + seg + 8);
    float4 c3 = *(const float4*)(cw + o*64 + seg + 12);
    h8 v0, v1;
    v0[0]=(_Float16)c0.x; v0[1]=(_Float16)c0.y; v0[2]=(_Float16)c0.z; v0[3]=(_Float16)c0.w;
    v0[4]=(_Float16)c1.x; v0[5]=(_Float16)c1.y; v0[6]=(_Float16)c1.z; v0[7]=(_Float16)c1.w;
    v1[0]=(_Float16)c2.x; v1[1]=(_Float16)c2.y; v1[2]=(_Float16)c2.z; v1[3]=(_Float16)c2.w;
    v1[4]=(_Float16)c3.x; v1[5]=(_Float16)c3.y; v1[6]=(_Float16)c3.z; v1[7]=(_Float16)c3.w;
    int cb0 = (seg>>3) ^ (o & 7);
    int cb1 = ((seg>>3)+1) ^ (o & 7);
    *(h8*)(At + o*128 + cb0*8) = v0;
    *(h8*)(At + o*128 + cb1*8) = v1;
  }
  {
    int o = tid >> 2, gq = tid & 3;
    const float* gp = G + ((size_t)(n*64+o)*128 + h)*32 + gq*8;
    float4 g0 = *(const float4*)(gp);
    float4 g1 = *(const float4*)(gp + 4);
    h8 v;
    v[0]=(_Float16)g0.x; v[1]=(_Float16)g0.y; v[2]=(_Float16)g0.z; v[3]=(_Float16)g0.w;
    v[4]=(_Float16)g1.x; v[5]=(_Float16)g1.y; v[6]=(_Float16)g1.z; v[7]=(_Float16)g1.w;
    int chunk = (8 + gq) ^ (o & 7);
    *(h8*)(At + o*128 + chunk*8) = v;
  }
  {
    int w = tid;
    const _Float16* tp = Tspec + w*32;
    #pragma unroll
    for (int cc=0; cc<4; ++cc){
      h8 v = *(const h8*)(tp + cc*8);
      int chunk = (8 + cc) ^ (w & 7);
      *(h8*)(Bx + w*128 + chunk*8) = v;
    }
  }
  __syncthreads();

  int lane = tid & 63;
  int l31 = lane & 31, l5 = lane >> 5;
  int w0 = tid >> 6;
  int mt = w0 & 1, ng = w0 >> 1;
  int o_lane = mt*32 + l31;

  h8 af[6];
  #pragma unroll
  for (int ks=0;ks<6;++ks){
    int kb = ks*16 + l5*8;
    int chunk = (kb>>3) ^ (o_lane & 7);
    af[ks] = *(const h8*)(At + o_lane*128 + chunk*8);
  }
  float bias[16];
  #pragma unroll
  for (int j=0;j<16;++j) bias[j] = cb[mt*32 + (j&3) + 8*(j>>2) + 4*l5];

  f16v acc[4];
  #pragma unroll
  for (int q=0;q<4;++q)
    #pragma unroll
    for (int j=0;j<16;++j) acc[q][j] = bias[j];

  #pragma unroll
  for (int q=0;q<4;++q){
    int w = (ng*4+q)*32 + l31;
    const _Float16* bbase = Bx + w*128;
    int w7 = w & 7;
    #pragma unroll
    for (int ks=0;ks<6;++ks){
      int kb = ks*16 + l5*8;
      int chunk = (kb>>3) ^ w7;
      h8 bf = *(const h8*)(bbase + chunk*8);
      acc[q] = __builtin_amdgcn_mfma_f32_32x32x16_f16(af[ks], bf, acc[q], 0,0,0);
    }
  }

  #pragma unroll
  for (int q=0;q<4;++q){
    int wcol = (ng*4+q)*32 + l31;
    #pragma unroll
    for (int j=0;j<16;++j){
      int o = mt*32 + (j&3) + 8*(j>>2) + 4*l5;
      float v = gelu_f(acc[q][j]);
      act_out[(size_t)(n*64+o)*32768 + (size_t)h*256 + wcol] = (_Float16)v;
    }
  }
}

// ---------------- downdim 1x1 conv (E=64 -> C=2), fp16 in ----------------
__global__ __launch_bounds__(256) void k_downdim(const _Float16* __restrict__ x, const float* __restrict__ wd,
                                                 const float* __restrict__ bd, float* __restrict__ out){
  size_t idx = (size_t)blockIdx.x*256 + threadIdx.x;
  int n = (int)(idx >> 15);
  int pos = (int)(idx & 32767);
  float a0 = bd[0], a1 = bd[1];
  const _Float16* xp = x + (size_t)n*2097152 + pos;
  for (int e=0;e<64;++e){
    float v = (float)xp[(size_t)e*32768];
    a0 += wd[e]*v;
    a1 += wd[64+e]*v;
  }
  out[(size_t)n*65536 + pos] = a0;
  out[(size_t)n*65536 + 32768 + pos] = a1;
}

extern "C" void kernel_launch(void* const* d_in, const int* in_sizes, int n_in,
                              void* d_out, int out_size, void* d_ws, size_t ws_size,
                              hipStream_t stream) {
  const float* sv  = (const float*)d_in[0];
  const float* upw = (const float*)d_in[1];
  const float* upb = (const float*)d_in[2];
  const float* smw = (const float*)d_in[3];
  const float* smb = (const float*)d_in[4];  // smooth bias: conv3x3 bias is removed by instance-norm (affine=False) mean-subtraction -> folded out; see note below
  const float* fwr = (const float*)d_in[5];
  const float* fwi = (const float*)d_in[6];
  const float* fcw = (const float*)d_in[7];
  const float* fcb = (const float*)d_in[8];
  const float* ddw = (const float*)d_in[9];
  const float* ddb = (const float*)d_in[10];
  float* out = (float*)d_out;
  (void)smb; // NOTE: smooth_b shifts every pixel of channel o uniformly; instance-norm subtracts
             // the per-(n,o) mean, so a constant per-o offset cancels exactly. Keff needs no smb term.

  float* W = (float*)d_ws;
  _Float16* actA = (_Float16*)W;                    // 20971520 halves
  _Float16* actB = (_Float16*)(W + 10485760);       // 20971520 halves
  float* Cy    = W + 20971520;                      // 2621440
  float* G     = W + 23592960;                      // 2621440
  float* coeff = W + 26214400;                      // 655360
  float* mo    = W + 26869760;                      // 655360
  float* part  = W + 27525120;                      // 655360
  float* stats = W + 28180480;                      // 1280
  float* Keff  = W + 28181760;                      // 4096
  float* twFwH = W + 28185856;                      // 8192
  float* twBwH = W + 28194048;                      // 8192
  _Float16* Tspec = (_Float16*)(W + 28202240);      // 8192 halves
  _Float16* TdftW = (_Float16*)(W + 28206336);      // 8192 halves

  k_tables<<<96,256,0,stream>>>(twFwH, twBwH, Tspec, TdftW);
  k_foldK<<<4,256,0,stream>>>(smw, upw, upb, Keff);
  k_statconv<<<1280,256,0,stream>>>(sv, Keff, part);
  k_stats2<<<640,256,0,stream>>>(part, stats);
  k_convnorm<<<1280,256,0,stream>>>(sv, Keff, stats, actA);

  _Float16* xa = actA; _Float16* xb = actB;
  for (int l=0;l<4;++l){
    k_dftW_mfma<<<640,256,0,stream>>>(xa, TdftW, Cy);
    k_dftH<<<640,256,0,stream>>>(Cy, twFwH, coeff);
    k_modemix<<<256,256,0,stream>>>(coeff, fwr + (size_t)l*2097152, fwi + (size_t)l*2097152, mo);
    k_idftH<<<640,256,0,stream>>>(mo, twBwH, G);
    k_combine_mfma<<<1280,256,0,stream>>>(xa, G, Tspec, fcw + (size_t)l*4096, fcb + (size_t)l*64, xb);
    _Float16* t = xa; xa = xb; xb = t;
  }
  k_downdim<<<1280,256,0,stream>>>(xa, ddw, ddb, out);
}